// Round 1
// baseline (4395.787 us; speedup 1.0000x reference)
//
#include <hip/hip_runtime.h>

#define NN 262144
#define NE 4194304
#define NLOGIT 4
#define NHID 16
#define ND 20   // NLOGIT + NHID
#define ND2 40  // 2*ND

// ---------------------------------------------------------------------------
// Dense layer: y[OUT] = x[IN] @ W[IN][OUT] + b[OUT], optional ReLU.
// Weights/bias in LDS, x/y in registers. float4 weight reads (ds_read_b128).
// ---------------------------------------------------------------------------
template<int IN, int OUT, bool RELU>
__device__ __forceinline__ void dense(const float* __restrict__ x, float* __restrict__ y,
                                      const float* __restrict__ sW, const float* __restrict__ sb) {
    #pragma unroll
    for (int j = 0; j < OUT; j++) y[j] = sb[j];
    #pragma unroll
    for (int i = 0; i < IN; i++) {
        float xi = x[i];
        const float4* w = reinterpret_cast<const float4*>(sW + i * OUT);
        #pragma unroll
        for (int j4 = 0; j4 < OUT / 4; j4++) {
            float4 wv = w[j4];
            y[j4*4+0] = fmaf(xi, wv.x, y[j4*4+0]);
            y[j4*4+1] = fmaf(xi, wv.y, y[j4*4+1]);
            y[j4*4+2] = fmaf(xi, wv.z, y[j4*4+2]);
            y[j4*4+3] = fmaf(xi, wv.w, y[j4*4+3]);
        }
    }
    if (RELU) {
        #pragma unroll
        for (int j = 0; j < OUT; j++) y[j] = fmaxf(y[j], 0.0f);
    }
}

__device__ __forceinline__ void lds_fill(float* dst, const float* src, int n, int tid, int nthreads) {
    for (int i = tid; i < n; i += nthreads) dst[i] = src[i];
}

// ---------------------------------------------------------------------------
// Kernel A: per-node edge-message MLP (20 -> 64 -> 32 -> 20). Also zeroes agg.
// msg[n][k] = MLP_e(concat(logits[n], hidden[n]))  -- sender-only dependence.
// ---------------------------------------------------------------------------
__global__ __launch_bounds__(256) void msg_mlp_kernel(
    const float* __restrict__ logits, const float* __restrict__ hidden,
    const float* __restrict__ W1, const float* __restrict__ b1,
    const float* __restrict__ W2, const float* __restrict__ b2,
    const float* __restrict__ W3, const float* __restrict__ b3,
    float* __restrict__ msg, float* __restrict__ agg)
{
    __shared__ float sW1[ND * 64], sb1[64], sW2[64 * 32], sb2[32], sW3[32 * ND], sb3[ND];
    const int tid = threadIdx.x;
    lds_fill(sW1, W1, ND * 64, tid, 256);
    lds_fill(sb1, b1, 64, tid, 256);
    lds_fill(sW2, W2, 64 * 32, tid, 256);
    lds_fill(sb2, b2, 32, tid, 256);
    lds_fill(sW3, W3, 32 * ND, tid, 256);
    lds_fill(sb3, b3, ND, tid, 256);
    __syncthreads();

    const int n = blockIdx.x * 256 + tid;
    if (n >= NN) return;

    float x[ND];
    {
        float4 l0 = reinterpret_cast<const float4*>(logits + (size_t)n * NLOGIT)[0];
        x[0] = l0.x; x[1] = l0.y; x[2] = l0.z; x[3] = l0.w;
        const float4* hd = reinterpret_cast<const float4*>(hidden + (size_t)n * NHID);
        #pragma unroll
        for (int q = 0; q < 4; q++) {
            float4 h = hd[q];
            x[4 + q*4 + 0] = h.x; x[4 + q*4 + 1] = h.y;
            x[4 + q*4 + 2] = h.z; x[4 + q*4 + 3] = h.w;
        }
    }

    float h1[64], h2[32], o[ND];
    dense<ND, 64, true>(x, h1, sW1, sb1);
    dense<64, 32, true>(h1, h2, sW2, sb2);
    dense<32, ND, false>(h2, o, sW3, sb3);

    float4* mout = reinterpret_cast<float4*>(msg + (size_t)n * ND);
    float4* aout = reinterpret_cast<float4*>(agg + (size_t)n * ND);
    #pragma unroll
    for (int q = 0; q < ND / 4; q++) {
        mout[q] = make_float4(o[q*4+0], o[q*4+1], o[q*4+2], o[q*4+3]);
        aout[q] = make_float4(0.f, 0.f, 0.f, 0.f);
    }
}

// ---------------------------------------------------------------------------
// Kernel B: edge scatter. agg[receivers[e]][:] += msg[senders[e]][:]
// ---------------------------------------------------------------------------
__global__ __launch_bounds__(256) void scatter_kernel(
    const int* __restrict__ senders, const int* __restrict__ receivers,
    const float* __restrict__ msg, float* __restrict__ agg)
{
    const int e = blockIdx.x * 256 + threadIdx.x;
    if (e >= NE) return;
    const int s = senders[e];
    const int r = receivers[e];
    const float4* m = reinterpret_cast<const float4*>(msg + (size_t)s * ND);
    float* a = agg + (size_t)r * ND;
    #pragma unroll
    for (int q = 0; q < ND / 4; q++) {
        float4 v = m[q];
        atomicAdd(a + q*4 + 0, v.x);
        atomicAdd(a + q*4 + 1, v.y);
        atomicAdd(a + q*4 + 2, v.z);
        atomicAdd(a + q*4 + 3, v.w);
    }
}

// ---------------------------------------------------------------------------
// Kernel C: per-node output MLP (40 -> 64 -> 32 -> 20), split write of
// updated_logits (first NN*4 of d_out) and updated_hidden (next NN*16).
// ---------------------------------------------------------------------------
__global__ __launch_bounds__(256) void node_mlp_kernel(
    const float* __restrict__ logits, const float* __restrict__ hidden,
    const float* __restrict__ agg,
    const float* __restrict__ W1, const float* __restrict__ b1,
    const float* __restrict__ W2, const float* __restrict__ b2,
    const float* __restrict__ W3, const float* __restrict__ b3,
    float* __restrict__ out)
{
    __shared__ float sW1[ND2 * 64], sb1[64], sW2[64 * 32], sb2[32], sW3[32 * ND], sb3[ND];
    const int tid = threadIdx.x;
    lds_fill(sW1, W1, ND2 * 64, tid, 256);
    lds_fill(sb1, b1, 64, tid, 256);
    lds_fill(sW2, W2, 64 * 32, tid, 256);
    lds_fill(sb2, b2, 32, tid, 256);
    lds_fill(sW3, W3, 32 * ND, tid, 256);
    lds_fill(sb3, b3, ND, tid, 256);
    __syncthreads();

    const int n = blockIdx.x * 256 + tid;
    if (n >= NN) return;

    float x[ND2];
    {
        float4 l0 = reinterpret_cast<const float4*>(logits + (size_t)n * NLOGIT)[0];
        x[0] = l0.x; x[1] = l0.y; x[2] = l0.z; x[3] = l0.w;
        const float4* hd = reinterpret_cast<const float4*>(hidden + (size_t)n * NHID);
        #pragma unroll
        for (int q = 0; q < 4; q++) {
            float4 h = hd[q];
            x[4 + q*4 + 0] = h.x; x[4 + q*4 + 1] = h.y;
            x[4 + q*4 + 2] = h.z; x[4 + q*4 + 3] = h.w;
        }
        const float4* ag = reinterpret_cast<const float4*>(agg + (size_t)n * ND);
        #pragma unroll
        for (int q = 0; q < ND / 4; q++) {
            float4 a = ag[q];
            x[ND + q*4 + 0] = a.x; x[ND + q*4 + 1] = a.y;
            x[ND + q*4 + 2] = a.z; x[ND + q*4 + 3] = a.w;
        }
    }

    float h1[64], h2[32], o[ND];
    dense<ND2, 64, true>(x, h1, sW1, sb1);
    dense<64, 32, true>(h1, h2, sW2, sb2);
    dense<32, ND, false>(h2, o, sW3, sb3);

    // updated_logits: out[0 .. NN*4)
    reinterpret_cast<float4*>(out + (size_t)n * NLOGIT)[0] =
        make_float4(o[0], o[1], o[2], o[3]);
    // updated_hidden: out[NN*4 .. NN*4 + NN*16)
    float4* ho = reinterpret_cast<float4*>(out + (size_t)NN * NLOGIT + (size_t)n * NHID);
    #pragma unroll
    for (int q = 0; q < 4; q++)
        ho[q] = make_float4(o[4 + q*4 + 0], o[4 + q*4 + 1], o[4 + q*4 + 2], o[4 + q*4 + 3]);
}

extern "C" void kernel_launch(void* const* d_in, const int* in_sizes, int n_in,
                              void* d_out, int out_size, void* d_ws, size_t ws_size,
                              hipStream_t stream) {
    const float* logits   = (const float*)d_in[0];
    const float* hidden   = (const float*)d_in[1];
    const int*   senders  = (const int*)d_in[2];
    const int*   receivers= (const int*)d_in[3];
    const float* We1 = (const float*)d_in[4];
    const float* be1 = (const float*)d_in[5];
    const float* We2 = (const float*)d_in[6];
    const float* be2 = (const float*)d_in[7];
    const float* We3 = (const float*)d_in[8];
    const float* be3 = (const float*)d_in[9];
    const float* Wn1 = (const float*)d_in[10];
    const float* bn1 = (const float*)d_in[11];
    const float* Wn2 = (const float*)d_in[12];
    const float* bn2 = (const float*)d_in[13];
    const float* Wn3 = (const float*)d_in[14];
    const float* bn3 = (const float*)d_in[15];
    float* out = (float*)d_out;

    float* msg = (float*)d_ws;                    // NN * ND floats = 21 MB
    float* agg = msg + (size_t)NN * ND;           // NN * ND floats = 21 MB

    msg_mlp_kernel<<<NN / 256, 256, 0, stream>>>(
        logits, hidden, We1, be1, We2, be2, We3, be3, msg, agg);
    scatter_kernel<<<NE / 256, 256, 0, stream>>>(senders, receivers, msg, agg);
    node_mlp_kernel<<<NN / 256, 256, 0, stream>>>(
        logits, hidden, agg, Wn1, bn1, Wn2, bn2, Wn3, bn3, out);
}

// Round 2
// 855.851 us; speedup vs baseline: 5.1362x; 5.1362x over previous
//
#include <hip/hip_runtime.h>

#define NN 262144
#define NE 4194304
#define NLOGIT 4
#define NHID 16
#define ND 20   // NLOGIT + NHID
#define ND2 40  // 2*ND
#define NBLK 1024  // NN / 256

// ---------------------------------------------------------------------------
// Dense layer: y[OUT] = x[IN] @ W[IN][OUT] + b[OUT], optional ReLU.
// ---------------------------------------------------------------------------
template<int IN, int OUT, bool RELU>
__device__ __forceinline__ void dense(const float* __restrict__ x, float* __restrict__ y,
                                      const float* __restrict__ sW, const float* __restrict__ sb) {
    #pragma unroll
    for (int j = 0; j < OUT; j++) y[j] = sb[j];
    #pragma unroll
    for (int i = 0; i < IN; i++) {
        float xi = x[i];
        const float4* w = reinterpret_cast<const float4*>(sW + i * OUT);
        #pragma unroll
        for (int j4 = 0; j4 < OUT / 4; j4++) {
            float4 wv = w[j4];
            y[j4*4+0] = fmaf(xi, wv.x, y[j4*4+0]);
            y[j4*4+1] = fmaf(xi, wv.y, y[j4*4+1]);
            y[j4*4+2] = fmaf(xi, wv.z, y[j4*4+2]);
            y[j4*4+3] = fmaf(xi, wv.w, y[j4*4+3]);
        }
    }
    if (RELU) {
        #pragma unroll
        for (int j = 0; j < OUT; j++) y[j] = fmaxf(y[j], 0.0f);
    }
}

__device__ __forceinline__ void lds_fill(float* dst, const float* src, int n, int tid, int nthreads) {
    for (int i = tid; i < n; i += nthreads) dst[i] = src[i];
}

// ---------------------------------------------------------------------------
// Kernel 1: per-node edge-message MLP (20 -> 64 -> 32 -> 20). Also zeroes deg.
// ---------------------------------------------------------------------------
__global__ __launch_bounds__(256) void msg_mlp_kernel(
    const float* __restrict__ logits, const float* __restrict__ hidden,
    const float* __restrict__ W1, const float* __restrict__ b1,
    const float* __restrict__ W2, const float* __restrict__ b2,
    const float* __restrict__ W3, const float* __restrict__ b3,
    float* __restrict__ msg, int* __restrict__ deg)
{
    __shared__ float sW1[ND * 64], sb1[64], sW2[64 * 32], sb2[32], sW3[32 * ND], sb3[ND];
    const int tid = threadIdx.x;
    lds_fill(sW1, W1, ND * 64, tid, 256);
    lds_fill(sb1, b1, 64, tid, 256);
    lds_fill(sW2, W2, 64 * 32, tid, 256);
    lds_fill(sb2, b2, 32, tid, 256);
    lds_fill(sW3, W3, 32 * ND, tid, 256);
    lds_fill(sb3, b3, ND, tid, 256);
    __syncthreads();

    const int n = blockIdx.x * 256 + tid;
    if (n >= NN) return;
    deg[n] = 0;

    float x[ND];
    {
        float4 l0 = reinterpret_cast<const float4*>(logits + (size_t)n * NLOGIT)[0];
        x[0] = l0.x; x[1] = l0.y; x[2] = l0.z; x[3] = l0.w;
        const float4* hd = reinterpret_cast<const float4*>(hidden + (size_t)n * NHID);
        #pragma unroll
        for (int q = 0; q < 4; q++) {
            float4 h = hd[q];
            x[4 + q*4 + 0] = h.x; x[4 + q*4 + 1] = h.y;
            x[4 + q*4 + 2] = h.z; x[4 + q*4 + 3] = h.w;
        }
    }

    float h1[64], h2[32], o[ND];
    dense<ND, 64, true>(x, h1, sW1, sb1);
    dense<64, 32, true>(h1, h2, sW2, sb2);
    dense<32, ND, false>(h2, o, sW3, sb3);

    float4* mout = reinterpret_cast<float4*>(msg + (size_t)n * ND);
    #pragma unroll
    for (int q = 0; q < ND / 4; q++)
        mout[q] = make_float4(o[q*4+0], o[q*4+1], o[q*4+2], o[q*4+3]);
}

// ---------------------------------------------------------------------------
// Kernel 2: histogram of receivers. deg[r]++ per edge.
// ---------------------------------------------------------------------------
__global__ __launch_bounds__(256) void hist_kernel(
    const int* __restrict__ receivers, int* __restrict__ deg)
{
    const int e = blockIdx.x * 256 + threadIdx.x;
    if (e < NE) atomicAdd(deg + receivers[e], 1);
}

// ---------------------------------------------------------------------------
// Kernel 3a/3b/3c: hierarchical exclusive scan of deg -> rowstart (+cursor copy)
// ---------------------------------------------------------------------------
__global__ __launch_bounds__(256) void scan_a_kernel(
    const int* __restrict__ deg, int* __restrict__ rowstart, int* __restrict__ bsum)
{
    __shared__ int s[256];
    const int tid = threadIdx.x;
    const int i = blockIdx.x * 256 + tid;
    const int v = deg[i];
    s[tid] = v;
    __syncthreads();
    #pragma unroll
    for (int off = 1; off < 256; off <<= 1) {
        int t = (tid >= off) ? s[tid - off] : 0;
        __syncthreads();
        s[tid] += t;
        __syncthreads();
    }
    rowstart[i] = s[tid] - v;             // exclusive, block-local
    if (tid == 255) bsum[blockIdx.x] = s[255];
}

__global__ __launch_bounds__(1024) void scan_b_kernel(int* __restrict__ bsum)
{
    __shared__ int s[NBLK];
    const int tid = threadIdx.x;
    const int v = bsum[tid];
    s[tid] = v;
    __syncthreads();
    #pragma unroll
    for (int off = 1; off < NBLK; off <<= 1) {
        int t = (tid >= off) ? s[tid - off] : 0;
        __syncthreads();
        s[tid] += t;
        __syncthreads();
    }
    bsum[tid] = s[tid] - v;               // exclusive block offsets
}

__global__ __launch_bounds__(256) void scan_c_kernel(
    int* __restrict__ rowstart, const int* __restrict__ bsum, int* __restrict__ cursor)
{
    const int i = blockIdx.x * 256 + threadIdx.x;
    const int v = rowstart[i] + bsum[blockIdx.x];
    rowstart[i] = v;
    cursor[i] = v;
}

// ---------------------------------------------------------------------------
// Kernel 4: fill CSR. csr[slot] = sender, slot = cursor[recv]++.
// After this kernel, cursor[r] == row end for r.
// ---------------------------------------------------------------------------
__global__ __launch_bounds__(256) void fill_kernel(
    const int* __restrict__ senders, const int* __restrict__ receivers,
    int* __restrict__ cursor, int* __restrict__ csr)
{
    const int e = blockIdx.x * 256 + threadIdx.x;
    if (e >= NE) return;
    const int r = receivers[e];
    const int slot = atomicAdd(cursor + r, 1);
    csr[slot] = senders[e];
}

// ---------------------------------------------------------------------------
// Kernel 5: gather. One wave per receiver; lanes 0..19 hold components.
// agg[r][c] = sum over incoming edges of msg[sender][c]. No atomics.
// ---------------------------------------------------------------------------
__global__ __launch_bounds__(256) void gather_kernel(
    const int* __restrict__ csr, const int* __restrict__ rowstart,
    const int* __restrict__ cursor, const float* __restrict__ msg,
    float* __restrict__ agg)
{
    const int gid = blockIdx.x * 256 + threadIdx.x;
    const int r = gid >> 6;               // one wave (64 lanes) per receiver
    const int lane = threadIdx.x & 63;
    if (r >= NN) return;

    const int base = rowstart[r];
    const int end = cursor[r];            // == rowstart[r] + deg[r]
    const bool act = lane < ND;
    const int c = lane;

    float a0 = 0.f, a1 = 0.f, a2 = 0.f, a3 = 0.f;
    int i = base;
    for (; i + 3 < end; i += 4) {
        const int s0 = csr[i + 0];
        const int s1 = csr[i + 1];
        const int s2 = csr[i + 2];
        const int s3 = csr[i + 3];
        if (act) {
            a0 += msg[s0 * ND + c];
            a1 += msg[s1 * ND + c];
            a2 += msg[s2 * ND + c];
            a3 += msg[s3 * ND + c];
        }
    }
    for (; i < end; i++) {
        const int s = csr[i];
        if (act) a0 += msg[s * ND + c];
    }
    if (act) agg[(size_t)r * ND + c] = (a0 + a1) + (a2 + a3);
}

// ---------------------------------------------------------------------------
// Kernel 6: per-node output MLP (40 -> 64 -> 32 -> 20).
// ---------------------------------------------------------------------------
__global__ __launch_bounds__(256) void node_mlp_kernel(
    const float* __restrict__ logits, const float* __restrict__ hidden,
    const float* __restrict__ agg,
    const float* __restrict__ W1, const float* __restrict__ b1,
    const float* __restrict__ W2, const float* __restrict__ b2,
    const float* __restrict__ W3, const float* __restrict__ b3,
    float* __restrict__ out)
{
    __shared__ float sW1[ND2 * 64], sb1[64], sW2[64 * 32], sb2[32], sW3[32 * ND], sb3[ND];
    const int tid = threadIdx.x;
    lds_fill(sW1, W1, ND2 * 64, tid, 256);
    lds_fill(sb1, b1, 64, tid, 256);
    lds_fill(sW2, W2, 64 * 32, tid, 256);
    lds_fill(sb2, b2, 32, tid, 256);
    lds_fill(sW3, W3, 32 * ND, tid, 256);
    lds_fill(sb3, b3, ND, tid, 256);
    __syncthreads();

    const int n = blockIdx.x * 256 + tid;
    if (n >= NN) return;

    float x[ND2];
    {
        float4 l0 = reinterpret_cast<const float4*>(logits + (size_t)n * NLOGIT)[0];
        x[0] = l0.x; x[1] = l0.y; x[2] = l0.z; x[3] = l0.w;
        const float4* hd = reinterpret_cast<const float4*>(hidden + (size_t)n * NHID);
        #pragma unroll
        for (int q = 0; q < 4; q++) {
            float4 h = hd[q];
            x[4 + q*4 + 0] = h.x; x[4 + q*4 + 1] = h.y;
            x[4 + q*4 + 2] = h.z; x[4 + q*4 + 3] = h.w;
        }
        const float4* ag = reinterpret_cast<const float4*>(agg + (size_t)n * ND);
        #pragma unroll
        for (int q = 0; q < ND / 4; q++) {
            float4 a = ag[q];
            x[ND + q*4 + 0] = a.x; x[ND + q*4 + 1] = a.y;
            x[ND + q*4 + 2] = a.z; x[ND + q*4 + 3] = a.w;
        }
    }

    float h1[64], h2[32], o[ND];
    dense<ND2, 64, true>(x, h1, sW1, sb1);
    dense<64, 32, true>(h1, h2, sW2, sb2);
    dense<32, ND, false>(h2, o, sW3, sb3);

    reinterpret_cast<float4*>(out + (size_t)n * NLOGIT)[0] =
        make_float4(o[0], o[1], o[2], o[3]);
    float4* ho = reinterpret_cast<float4*>(out + (size_t)NN * NLOGIT + (size_t)n * NHID);
    #pragma unroll
    for (int q = 0; q < 4; q++)
        ho[q] = make_float4(o[4 + q*4 + 0], o[4 + q*4 + 1], o[4 + q*4 + 2], o[4 + q*4 + 3]);
}

extern "C" void kernel_launch(void* const* d_in, const int* in_sizes, int n_in,
                              void* d_out, int out_size, void* d_ws, size_t ws_size,
                              hipStream_t stream) {
    const float* logits   = (const float*)d_in[0];
    const float* hidden   = (const float*)d_in[1];
    const int*   senders  = (const int*)d_in[2];
    const int*   receivers= (const int*)d_in[3];
    const float* We1 = (const float*)d_in[4];
    const float* be1 = (const float*)d_in[5];
    const float* We2 = (const float*)d_in[6];
    const float* be2 = (const float*)d_in[7];
    const float* We3 = (const float*)d_in[8];
    const float* be3 = (const float*)d_in[9];
    const float* Wn1 = (const float*)d_in[10];
    const float* bn1 = (const float*)d_in[11];
    const float* Wn2 = (const float*)d_in[12];
    const float* bn2 = (const float*)d_in[13];
    const float* Wn3 = (const float*)d_in[14];
    const float* bn3 = (const float*)d_in[15];
    float* out = (float*)d_out;

    // Workspace layout (~62 MB total)
    float* msg = (float*)d_ws;                      // NN*ND floats (21 MB)
    float* agg = msg + (size_t)NN * ND;             // NN*ND floats (21 MB)
    int* deg      = (int*)(agg + (size_t)NN * ND);  // NN ints
    int* rowstart = deg + NN;                       // NN ints
    int* cursor   = rowstart + NN;                  // NN ints
    int* bsum     = cursor + NN;                    // NBLK ints
    int* csr      = bsum + NBLK;                    // NE ints (16.8 MB)

    msg_mlp_kernel<<<NN / 256, 256, 0, stream>>>(
        logits, hidden, We1, be1, We2, be2, We3, be3, msg, deg);
    hist_kernel<<<NE / 256, 256, 0, stream>>>(receivers, deg);
    scan_a_kernel<<<NBLK, 256, 0, stream>>>(deg, rowstart, bsum);
    scan_b_kernel<<<1, NBLK, 0, stream>>>(bsum);
    scan_c_kernel<<<NBLK, 256, 0, stream>>>(rowstart, bsum, cursor);
    fill_kernel<<<NE / 256, 256, 0, stream>>>(senders, receivers, cursor, csr);
    gather_kernel<<<(NN * 64) / 256, 256, 0, stream>>>(csr, rowstart, cursor, msg, agg);
    node_mlp_kernel<<<NN / 256, 256, 0, stream>>>(
        logits, hidden, agg, Wn1, bn1, Wn2, bn2, Wn3, bn3, out);
}

// Round 3
// 351.191 us; speedup vs baseline: 12.5168x; 2.4370x over previous
//
#include <hip/hip_runtime.h>

#define NN 262144
#define NE 4194304
#define NLOGIT 4
#define NHID 16
#define ND 20   // NLOGIT + NHID
#define ND2 40  // 2*ND

#define NBUCK 512          // buckets
#define BSHIFT 9           // bucket = receiver >> BSHIFT
#define RPB 512            // receivers per bucket (NN / NBUCK)
#define SBITS 18           // sender id bits (NN = 2^18)
#define SMASK ((1u << SBITS) - 1)
#define FBLK 1024          // blocks in hist/fill
#define EPB (NE / FBLK)    // 4096 edges per block
#define EPT (EPB / 256)    // 16 edges per thread
#define CAP 9728           // per-bucket LDS edge capacity (mean 8192, +17 sigma)

// ---------------------------------------------------------------------------
// Dense layer: y[OUT] = x[IN] @ W[IN][OUT] + b[OUT], optional ReLU.
// ---------------------------------------------------------------------------
template<int IN, int OUT, bool RELU>
__device__ __forceinline__ void dense(const float* __restrict__ x, float* __restrict__ y,
                                      const float* __restrict__ sW, const float* __restrict__ sb) {
    #pragma unroll
    for (int j = 0; j < OUT; j++) y[j] = sb[j];
    #pragma unroll
    for (int i = 0; i < IN; i++) {
        float xi = x[i];
        const float4* w = reinterpret_cast<const float4*>(sW + i * OUT);
        #pragma unroll
        for (int j4 = 0; j4 < OUT / 4; j4++) {
            float4 wv = w[j4];
            y[j4*4+0] = fmaf(xi, wv.x, y[j4*4+0]);
            y[j4*4+1] = fmaf(xi, wv.y, y[j4*4+1]);
            y[j4*4+2] = fmaf(xi, wv.z, y[j4*4+2]);
            y[j4*4+3] = fmaf(xi, wv.w, y[j4*4+3]);
        }
    }
    if (RELU) {
        #pragma unroll
        for (int j = 0; j < OUT; j++) y[j] = fmaxf(y[j], 0.0f);
    }
}

__device__ __forceinline__ void lds_fill(float* dst, const float* src, int n, int tid, int nthreads) {
    for (int i = tid; i < n; i += nthreads) dst[i] = src[i];
}

// ---------------------------------------------------------------------------
// Kernel 1: per-node edge-message MLP (20 -> 64 -> 32 -> 20). Block 0 zeroes bcnt.
// ---------------------------------------------------------------------------
__global__ __launch_bounds__(256) void msg_mlp_kernel(
    const float* __restrict__ logits, const float* __restrict__ hidden,
    const float* __restrict__ W1, const float* __restrict__ b1,
    const float* __restrict__ W2, const float* __restrict__ b2,
    const float* __restrict__ W3, const float* __restrict__ b3,
    float* __restrict__ msg, int* __restrict__ bcnt)
{
    __shared__ float sW1[ND * 64], sb1[64], sW2[64 * 32], sb2[32], sW3[32 * ND], sb3[ND];
    const int tid = threadIdx.x;
    if (blockIdx.x == 0) { bcnt[tid] = 0; bcnt[256 + tid] = 0; }
    lds_fill(sW1, W1, ND * 64, tid, 256);
    lds_fill(sb1, b1, 64, tid, 256);
    lds_fill(sW2, W2, 64 * 32, tid, 256);
    lds_fill(sb2, b2, 32, tid, 256);
    lds_fill(sW3, W3, 32 * ND, tid, 256);
    lds_fill(sb3, b3, ND, tid, 256);
    __syncthreads();

    const int n = blockIdx.x * 256 + tid;
    if (n >= NN) return;

    float x[ND];
    {
        float4 l0 = reinterpret_cast<const float4*>(logits + (size_t)n * NLOGIT)[0];
        x[0] = l0.x; x[1] = l0.y; x[2] = l0.z; x[3] = l0.w;
        const float4* hd = reinterpret_cast<const float4*>(hidden + (size_t)n * NHID);
        #pragma unroll
        for (int q = 0; q < 4; q++) {
            float4 h = hd[q];
            x[4 + q*4 + 0] = h.x; x[4 + q*4 + 1] = h.y;
            x[4 + q*4 + 2] = h.z; x[4 + q*4 + 3] = h.w;
        }
    }

    float h1[64], h2[32], o[ND];
    dense<ND, 64, true>(x, h1, sW1, sb1);
    dense<64, 32, true>(h1, h2, sW2, sb2);
    dense<32, ND, false>(h2, o, sW3, sb3);

    float4* mout = reinterpret_cast<float4*>(msg + (size_t)n * ND);
    #pragma unroll
    for (int q = 0; q < ND / 4; q++)
        mout[q] = make_float4(o[q*4+0], o[q*4+1], o[q*4+2], o[q*4+3]);
}

// ---------------------------------------------------------------------------
// Kernel 2: bucket histogram. LDS-aggregated; 512 global atomics per 4096 edges.
// ---------------------------------------------------------------------------
__global__ __launch_bounds__(256) void bucket_hist_kernel(
    const int* __restrict__ receivers, int* __restrict__ bcnt)
{
    __shared__ int cnt[NBUCK];
    const int tid = threadIdx.x;
    cnt[tid] = 0; cnt[256 + tid] = 0;
    __syncthreads();
    const int base = blockIdx.x * EPB;
    #pragma unroll
    for (int k = 0; k < EPT; k++) {
        const int r = receivers[base + k * 256 + tid];
        atomicAdd(&cnt[r >> BSHIFT], 1);
    }
    __syncthreads();
    #pragma unroll
    for (int j = tid; j < NBUCK; j += 256)
        if (cnt[j] > 0) atomicAdd(&bcnt[j], cnt[j]);
}

// ---------------------------------------------------------------------------
// Kernel 3: exclusive scan of bcnt -> bbase, bcur. One block.
// ---------------------------------------------------------------------------
__global__ __launch_bounds__(NBUCK) void bucket_scan_kernel(
    const int* __restrict__ bcnt, int* __restrict__ bbase, int* __restrict__ bcur)
{
    __shared__ int s[NBUCK];
    const int tid = threadIdx.x;
    const int v = bcnt[tid];
    s[tid] = v;
    __syncthreads();
    #pragma unroll
    for (int off = 1; off < NBUCK; off <<= 1) {
        int t = (tid >= off) ? s[tid - off] : 0;
        __syncthreads();
        s[tid] += t;
        __syncthreads();
    }
    const int ex = s[tid] - v;
    bbase[tid] = ex;
    bcur[tid] = ex;
}

// ---------------------------------------------------------------------------
// Kernel 4: bucket fill. Per-block LDS histogram + one global reservation per
// (block,bucket); writes cluster ~8 consecutive u32 per (block,bucket).
// Entry: (rlocal << 18) | sender.
// ---------------------------------------------------------------------------
__global__ __launch_bounds__(256) void bucket_fill_kernel(
    const int* __restrict__ senders, const int* __restrict__ receivers,
    int* __restrict__ bcur, unsigned int* __restrict__ bucketed)
{
    __shared__ int cnt[NBUCK];
    __shared__ int lcur[NBUCK];
    const int tid = threadIdx.x;
    cnt[tid] = 0; cnt[256 + tid] = 0;
    __syncthreads();
    const int base = blockIdx.x * EPB;
    #pragma unroll
    for (int k = 0; k < EPT; k++) {
        const int r = receivers[base + k * 256 + tid];
        atomicAdd(&cnt[r >> BSHIFT], 1);
    }
    __syncthreads();
    #pragma unroll
    for (int j = tid; j < NBUCK; j += 256) {
        const int c = cnt[j];
        lcur[j] = (c > 0) ? atomicAdd(&bcur[j], c) : 0;
    }
    __syncthreads();
    #pragma unroll
    for (int k = 0; k < EPT; k++) {
        const int idx = base + k * 256 + tid;
        const int r = receivers[idx];
        const unsigned int sv = (unsigned int)senders[idx];
        const int b = r >> BSHIFT;
        const int slot = atomicAdd(&lcur[b], 1);
        bucketed[slot] = (((unsigned int)(r & (RPB - 1))) << SBITS) | sv;
    }
}

// ---------------------------------------------------------------------------
// Kernel 5: fused per-bucket group + gather. One block per bucket.
// Groups the bucket's edges by receiver in LDS (all atomics in LDS), then
// half-wave (32-lane) groups gather msg rows per receiver. No global atomics.
// ---------------------------------------------------------------------------
__global__ __launch_bounds__(1024) void bucket_gather_kernel(
    const unsigned int* __restrict__ bucketed,
    const int* __restrict__ bbase, const int* __restrict__ bcur,
    const float* __restrict__ msg, float* __restrict__ agg)
{
    __shared__ unsigned int elds[CAP];
    __shared__ int dcnt[RPB];
    __shared__ int dcur[RPB];
    const int tid = threadIdx.x;
    const int b = blockIdx.x;
    const int gs = bbase[b];
    const int ge = bcur[b];           // after fill: end of bucket
    const int nb = ge - gs;

    if (tid < RPB) dcnt[tid] = 0;
    __syncthreads();
    for (int i = tid; i < nb; i += 1024)
        atomicAdd(&dcnt[bucketed[gs + i] >> SBITS], 1);
    __syncthreads();
    // exclusive scan of dcnt into dcur
    if (tid < RPB) dcur[tid] = dcnt[tid];
    __syncthreads();
    #pragma unroll
    for (int off = 1; off < RPB; off <<= 1) {
        int t = 0;
        if (tid < RPB && tid >= off) t = dcur[tid - off];
        __syncthreads();
        if (tid < RPB) dcur[tid] += t;
        __syncthreads();
    }
    if (tid < RPB) dcur[tid] -= dcnt[tid];   // exclusive
    __syncthreads();
    for (int i = tid; i < nb; i += 1024) {
        const unsigned int v = bucketed[gs + i];
        const int rl = v >> SBITS;
        const int slot = atomicAdd(&dcur[rl], 1);
        if (slot < CAP) elds[slot] = v & SMASK;
    }
    __syncthreads();

    // gather: half-wave groups, lanes 0..19 = components
    const int hw = tid >> 5;          // 0..31
    const int c = tid & 31;
    const bool act = c < ND;
    for (int rl = hw; rl < RPB; rl += 32) {
        int end = dcur[rl];           // == start + cnt
        const int cv = dcnt[rl];
        int st = end - cv;
        if (st < 0) st = 0;
        if (end > CAP) end = CAP;
        float a0 = 0.f, a1 = 0.f, a2 = 0.f, a3 = 0.f;
        int i = st;
        for (; i + 3 < end; i += 4) {
            const int s0 = elds[i + 0];
            const int s1 = elds[i + 1];
            const int s2 = elds[i + 2];
            const int s3 = elds[i + 3];
            if (act) {
                a0 += msg[s0 * ND + c];
                a1 += msg[s1 * ND + c];
                a2 += msg[s2 * ND + c];
                a3 += msg[s3 * ND + c];
            }
        }
        for (; i < end; i++) {
            const int s = elds[i];
            if (act) a0 += msg[s * ND + c];
        }
        if (act) agg[((size_t)b * RPB + rl) * ND + c] = (a0 + a1) + (a2 + a3);
    }
}

// ---------------------------------------------------------------------------
// Kernel 6: per-node output MLP (40 -> 64 -> 32 -> 20).
// ---------------------------------------------------------------------------
__global__ __launch_bounds__(256) void node_mlp_kernel(
    const float* __restrict__ logits, const float* __restrict__ hidden,
    const float* __restrict__ agg,
    const float* __restrict__ W1, const float* __restrict__ b1,
    const float* __restrict__ W2, const float* __restrict__ b2,
    const float* __restrict__ W3, const float* __restrict__ b3,
    float* __restrict__ out)
{
    __shared__ float sW1[ND2 * 64], sb1[64], sW2[64 * 32], sb2[32], sW3[32 * ND], sb3[ND];
    const int tid = threadIdx.x;
    lds_fill(sW1, W1, ND2 * 64, tid, 256);
    lds_fill(sb1, b1, 64, tid, 256);
    lds_fill(sW2, W2, 64 * 32, tid, 256);
    lds_fill(sb2, b2, 32, tid, 256);
    lds_fill(sW3, W3, 32 * ND, tid, 256);
    lds_fill(sb3, b3, ND, tid, 256);
    __syncthreads();

    const int n = blockIdx.x * 256 + tid;
    if (n >= NN) return;

    float x[ND2];
    {
        float4 l0 = reinterpret_cast<const float4*>(logits + (size_t)n * NLOGIT)[0];
        x[0] = l0.x; x[1] = l0.y; x[2] = l0.z; x[3] = l0.w;
        const float4* hd = reinterpret_cast<const float4*>(hidden + (size_t)n * NHID);
        #pragma unroll
        for (int q = 0; q < 4; q++) {
            float4 h = hd[q];
            x[4 + q*4 + 0] = h.x; x[4 + q*4 + 1] = h.y;
            x[4 + q*4 + 2] = h.z; x[4 + q*4 + 3] = h.w;
        }
        const float4* ag = reinterpret_cast<const float4*>(agg + (size_t)n * ND);
        #pragma unroll
        for (int q = 0; q < ND / 4; q++) {
            float4 a = ag[q];
            x[ND + q*4 + 0] = a.x; x[ND + q*4 + 1] = a.y;
            x[ND + q*4 + 2] = a.z; x[ND + q*4 + 3] = a.w;
        }
    }

    float h1[64], h2[32], o[ND];
    dense<ND2, 64, true>(x, h1, sW1, sb1);
    dense<64, 32, true>(h1, h2, sW2, sb2);
    dense<32, ND, false>(h2, o, sW3, sb3);

    reinterpret_cast<float4*>(out + (size_t)n * NLOGIT)[0] =
        make_float4(o[0], o[1], o[2], o[3]);
    float4* ho = reinterpret_cast<float4*>(out + (size_t)NN * NLOGIT + (size_t)n * NHID);
    #pragma unroll
    for (int q = 0; q < 4; q++)
        ho[q] = make_float4(o[4 + q*4 + 0], o[4 + q*4 + 1], o[4 + q*4 + 2], o[4 + q*4 + 3]);
}

extern "C" void kernel_launch(void* const* d_in, const int* in_sizes, int n_in,
                              void* d_out, int out_size, void* d_ws, size_t ws_size,
                              hipStream_t stream) {
    const float* logits   = (const float*)d_in[0];
    const float* hidden   = (const float*)d_in[1];
    const int*   senders  = (const int*)d_in[2];
    const int*   receivers= (const int*)d_in[3];
    const float* We1 = (const float*)d_in[4];
    const float* be1 = (const float*)d_in[5];
    const float* We2 = (const float*)d_in[6];
    const float* be2 = (const float*)d_in[7];
    const float* We3 = (const float*)d_in[8];
    const float* be3 = (const float*)d_in[9];
    const float* Wn1 = (const float*)d_in[10];
    const float* bn1 = (const float*)d_in[11];
    const float* Wn2 = (const float*)d_in[12];
    const float* bn2 = (const float*)d_in[13];
    const float* Wn3 = (const float*)d_in[14];
    const float* bn3 = (const float*)d_in[15];
    float* out = (float*)d_out;

    // Workspace layout (~58.8 MB)
    float* msg = (float*)d_ws;                         // NN*ND floats (21 MB)
    float* agg = msg + (size_t)NN * ND;                // NN*ND floats (21 MB)
    unsigned int* bucketed = (unsigned int*)(agg + (size_t)NN * ND);  // NE u32 (16.8 MB)
    int* bcnt  = (int*)(bucketed + NE);                // NBUCK ints
    int* bbase = bcnt + NBUCK;                         // NBUCK ints
    int* bcur  = bbase + NBUCK;                        // NBUCK ints

    msg_mlp_kernel<<<NN / 256, 256, 0, stream>>>(
        logits, hidden, We1, be1, We2, be2, We3, be3, msg, bcnt);
    bucket_hist_kernel<<<FBLK, 256, 0, stream>>>(receivers, bcnt);
    bucket_scan_kernel<<<1, NBUCK, 0, stream>>>(bcnt, bbase, bcur);
    bucket_fill_kernel<<<FBLK, 256, 0, stream>>>(senders, receivers, bcur, bucketed);
    bucket_gather_kernel<<<NBUCK, 1024, 0, stream>>>(bucketed, bbase, bcur, msg, agg);
    node_mlp_kernel<<<NN / 256, 256, 0, stream>>>(
        logits, hidden, agg, Wn1, bn1, Wn2, bn2, Wn3, bn3, out);
}

// Round 4
// 296.838 us; speedup vs baseline: 14.8087x; 1.1831x over previous
//
#include <hip/hip_runtime.h>

#define NN 262144
#define NE 4194304
#define NLOGIT 4
#define NHID 16
#define ND 20   // NLOGIT + NHID
#define ND2 40  // 2*ND

#define NBUCK 512          // buckets
#define BSHIFT 9           // bucket = receiver >> BSHIFT
#define RPB 512            // receivers per bucket (NN / NBUCK)
#define SBITS 18           // sender id bits (NN = 2^18)
#define SMASK ((1u << SBITS) - 1)
#define FBLK 1024          // blocks in hist/fill
#define EPB (NE / FBLK)    // 4096 edges per block
#define EPT (EPB / 256)    // 16 edges per thread
#define CAP 9728           // per-bucket LDS edge capacity (mean 8192, +17 sigma)

#define NPB 128            // nodes per MLP block
#define XS 132             // padded LDS column stride (132 % 32 = 4 -> de-conflicted)

__device__ __forceinline__ void lds_fill(float* dst, const float* src, int n, int tid, int nthreads) {
    for (int i = tid; i < n; i += nthreads) dst[i] = src[i];
}

// ---------------------------------------------------------------------------
// Register-blocked 3-layer MLP core over a 128-node LDS tile.
// Thread t: node quad q = t&31 (nodes q*4..q*4+3), feature group g = t>>5.
// L1: IN->64 (8 feats/thread), L2: 64->32 (4 feats/thread),
// L3: 32->20 (groups 0..4, 4 feats/thread).
// Xl: [IN][XS] transposed input. H1: [64][XS]. H2: [32][XS] (may alias Xl).
// Ol: [NPB][20] output staging (may alias H2 region). Barriers inside.
// ---------------------------------------------------------------------------
template<int IN>
__device__ __forceinline__ void mlp3_core(
    const int tid, const float* Xl, float* H1, float* H2, float* Ol,
    const float* sW1, const float* sb1,
    const float* sW2, const float* sb2,
    const float* sW3, const float* sb3)
{
    const int q = tid & 31;
    const int g = tid >> 5;
    const int n0 = q * 4;

    // ---- layer 1: IN -> 64, feats g*8 .. g*8+7, nodes n0..n0+3
    float a1[8][4];
    #pragma unroll
    for (int f = 0; f < 8; f++) {
        const float b = sb1[g * 8 + f];
        a1[f][0] = b; a1[f][1] = b; a1[f][2] = b; a1[f][3] = b;
    }
    #pragma unroll
    for (int i = 0; i < IN; i++) {
        const float4 xv = *reinterpret_cast<const float4*>(&Xl[i * XS + n0]);
        const float4 w0 = *reinterpret_cast<const float4*>(&sW1[i * 64 + g * 8]);
        const float4 w1 = *reinterpret_cast<const float4*>(&sW1[i * 64 + g * 8 + 4]);
        const float wf[8] = {w0.x, w0.y, w0.z, w0.w, w1.x, w1.y, w1.z, w1.w};
        #pragma unroll
        for (int f = 0; f < 8; f++) {
            a1[f][0] = fmaf(xv.x, wf[f], a1[f][0]);
            a1[f][1] = fmaf(xv.y, wf[f], a1[f][1]);
            a1[f][2] = fmaf(xv.z, wf[f], a1[f][2]);
            a1[f][3] = fmaf(xv.w, wf[f], a1[f][3]);
        }
    }
    #pragma unroll
    for (int f = 0; f < 8; f++) {
        float4 v = make_float4(fmaxf(a1[f][0], 0.f), fmaxf(a1[f][1], 0.f),
                               fmaxf(a1[f][2], 0.f), fmaxf(a1[f][3], 0.f));
        *reinterpret_cast<float4*>(&H1[(g * 8 + f) * XS + n0]) = v;
    }
    __syncthreads();   // H1 complete; Xl dead from here (H2 may alias it)

    // ---- layer 2: 64 -> 32, feats g*4 .. g*4+3
    float a2[4][4];
    #pragma unroll
    for (int f = 0; f < 4; f++) {
        const float b = sb2[g * 4 + f];
        a2[f][0] = b; a2[f][1] = b; a2[f][2] = b; a2[f][3] = b;
    }
    #pragma unroll
    for (int i = 0; i < 64; i++) {
        const float4 xv = *reinterpret_cast<const float4*>(&H1[i * XS + n0]);
        const float4 w = *reinterpret_cast<const float4*>(&sW2[i * 32 + g * 4]);
        const float wf[4] = {w.x, w.y, w.z, w.w};
        #pragma unroll
        for (int f = 0; f < 4; f++) {
            a2[f][0] = fmaf(xv.x, wf[f], a2[f][0]);
            a2[f][1] = fmaf(xv.y, wf[f], a2[f][1]);
            a2[f][2] = fmaf(xv.z, wf[f], a2[f][2]);
            a2[f][3] = fmaf(xv.w, wf[f], a2[f][3]);
        }
    }
    #pragma unroll
    for (int f = 0; f < 4; f++) {
        float4 v = make_float4(fmaxf(a2[f][0], 0.f), fmaxf(a2[f][1], 0.f),
                               fmaxf(a2[f][2], 0.f), fmaxf(a2[f][3], 0.f));
        *reinterpret_cast<float4*>(&H2[(g * 4 + f) * XS + n0]) = v;
    }
    __syncthreads();   // H2 complete

    // ---- layer 3: 32 -> 20, groups 0..4 active, feats g*4 .. g*4+3
    float a3[4][4];
    if (g < 5) {
        #pragma unroll
        for (int f = 0; f < 4; f++) {
            const float b = sb3[g * 4 + f];
            a3[f][0] = b; a3[f][1] = b; a3[f][2] = b; a3[f][3] = b;
        }
        #pragma unroll
        for (int i = 0; i < 32; i++) {
            const float4 xv = *reinterpret_cast<const float4*>(&H2[i * XS + n0]);
            const float4 w = *reinterpret_cast<const float4*>(&sW3[i * 20 + g * 4]);
            const float wf[4] = {w.x, w.y, w.z, w.w};
            #pragma unroll
            for (int f = 0; f < 4; f++) {
                a3[f][0] = fmaf(xv.x, wf[f], a3[f][0]);
                a3[f][1] = fmaf(xv.y, wf[f], a3[f][1]);
                a3[f][2] = fmaf(xv.z, wf[f], a3[f][2]);
                a3[f][3] = fmaf(xv.w, wf[f], a3[f][3]);
            }
        }
    }
    __syncthreads();   // all H2 reads done; Ol may alias H2
    if (g < 5) {
        #pragma unroll
        for (int f = 0; f < 4; f++) {
            #pragma unroll
            for (int k = 0; k < 4; k++)
                Ol[(n0 + k) * ND + g * 4 + f] = a3[f][k];
        }
    }
    __syncthreads();   // Ol ready for epilogue
}

// ---------------------------------------------------------------------------
// Kernel 1: edge-message MLP (20 -> 64 -> 32 -> 20), 128 nodes per block.
// Block 0 zeroes bcnt.
// ---------------------------------------------------------------------------
__global__ __launch_bounds__(256) void msg_mlp_kernel(
    const float* __restrict__ logits, const float* __restrict__ hidden,
    const float* __restrict__ W1, const float* __restrict__ b1,
    const float* __restrict__ W2, const float* __restrict__ b2,
    const float* __restrict__ W3, const float* __restrict__ b3,
    float* __restrict__ msg, int* __restrict__ bcnt)
{
    // region A: max(X 20*XS, H2 32*XS, Ol 128*20) = 32*XS floats
    __shared__ float regA[32 * XS];
    __shared__ float H1[64 * XS];
    __shared__ float sW1[ND * 64], sb1[64], sW2[64 * 32], sb2[32], sW3[32 * ND], sb3[ND];
    const int tid = threadIdx.x;
    const int nb0 = blockIdx.x * NPB;

    if (blockIdx.x == 0) { bcnt[tid] = 0; bcnt[256 + tid] = 0; }

    lds_fill(sW1, W1, ND * 64, tid, 256);
    lds_fill(sb1, b1, 64, tid, 256);
    lds_fill(sW2, W2, 64 * 32, tid, 256);
    lds_fill(sb2, b2, 32, tid, 256);
    lds_fill(sW3, W3, 32 * ND, tid, 256);
    lds_fill(sb3, b3, ND, tid, 256);

    float* Xl = regA;
    // stage logits -> rows 0..3
    if (tid < NPB) {
        const float4 lv = reinterpret_cast<const float4*>(logits)[nb0 + tid];
        Xl[0 * XS + tid] = lv.x; Xl[1 * XS + tid] = lv.y;
        Xl[2 * XS + tid] = lv.z; Xl[3 * XS + tid] = lv.w;
    }
    // stage hidden -> rows 4..19 (128 nodes x 4 float4 = 512)
    #pragma unroll
    for (int u = 0; u < 2; u++) {
        const int idx = u * 256 + tid;
        const int n = idx >> 2, qq = idx & 3;
        const float4 hv = reinterpret_cast<const float4*>(hidden)[(size_t)(nb0 + n) * 4 + qq];
        Xl[(4 + qq * 4 + 0) * XS + n] = hv.x;
        Xl[(4 + qq * 4 + 1) * XS + n] = hv.y;
        Xl[(4 + qq * 4 + 2) * XS + n] = hv.z;
        Xl[(4 + qq * 4 + 3) * XS + n] = hv.w;
    }
    __syncthreads();

    mlp3_core<ND>(tid, Xl, H1, regA /*H2*/, regA /*Ol*/, sW1, sb1, sW2, sb2, sW3, sb3);

    // epilogue: msg tile is contiguous NPB*20 floats = 640 float4
    const float4* Ol4 = reinterpret_cast<const float4*>(regA);
    float4* mo = reinterpret_cast<float4*>(msg + (size_t)nb0 * ND);
    #pragma unroll
    for (int idx = tid; idx < NPB * ND / 4; idx += 256)
        mo[idx] = Ol4[idx];
}

// ---------------------------------------------------------------------------
// Kernel 2: bucket histogram. LDS-aggregated; 512 global atomics per 4096 edges.
// ---------------------------------------------------------------------------
__global__ __launch_bounds__(256) void bucket_hist_kernel(
    const int* __restrict__ receivers, int* __restrict__ bcnt)
{
    __shared__ int cnt[NBUCK];
    const int tid = threadIdx.x;
    cnt[tid] = 0; cnt[256 + tid] = 0;
    __syncthreads();
    const int base = blockIdx.x * EPB;
    #pragma unroll
    for (int k = 0; k < EPT; k++) {
        const int r = receivers[base + k * 256 + tid];
        atomicAdd(&cnt[r >> BSHIFT], 1);
    }
    __syncthreads();
    #pragma unroll
    for (int j = tid; j < NBUCK; j += 256)
        if (cnt[j] > 0) atomicAdd(&bcnt[j], cnt[j]);
}

// ---------------------------------------------------------------------------
// Kernel 3: exclusive scan of bcnt -> bbase, bcur. One block.
// ---------------------------------------------------------------------------
__global__ __launch_bounds__(NBUCK) void bucket_scan_kernel(
    const int* __restrict__ bcnt, int* __restrict__ bbase, int* __restrict__ bcur)
{
    __shared__ int s[NBUCK];
    const int tid = threadIdx.x;
    const int v = bcnt[tid];
    s[tid] = v;
    __syncthreads();
    #pragma unroll
    for (int off = 1; off < NBUCK; off <<= 1) {
        int t = (tid >= off) ? s[tid - off] : 0;
        __syncthreads();
        s[tid] += t;
        __syncthreads();
    }
    const int ex = s[tid] - v;
    bbase[tid] = ex;
    bcur[tid] = ex;
}

// ---------------------------------------------------------------------------
// Kernel 4: bucket fill. Per-block LDS histogram + one global reservation per
// (block,bucket). Entry: (rlocal << 18) | sender.
// ---------------------------------------------------------------------------
__global__ __launch_bounds__(256) void bucket_fill_kernel(
    const int* __restrict__ senders, const int* __restrict__ receivers,
    int* __restrict__ bcur, unsigned int* __restrict__ bucketed)
{
    __shared__ int cnt[NBUCK];
    __shared__ int lcur[NBUCK];
    const int tid = threadIdx.x;
    cnt[tid] = 0; cnt[256 + tid] = 0;
    __syncthreads();
    const int base = blockIdx.x * EPB;
    #pragma unroll
    for (int k = 0; k < EPT; k++) {
        const int r = receivers[base + k * 256 + tid];
        atomicAdd(&cnt[r >> BSHIFT], 1);
    }
    __syncthreads();
    #pragma unroll
    for (int j = tid; j < NBUCK; j += 256) {
        const int c = cnt[j];
        lcur[j] = (c > 0) ? atomicAdd(&bcur[j], c) : 0;
    }
    __syncthreads();
    #pragma unroll
    for (int k = 0; k < EPT; k++) {
        const int idx = base + k * 256 + tid;
        const int r = receivers[idx];
        const unsigned int sv = (unsigned int)senders[idx];
        const int b = r >> BSHIFT;
        const int slot = atomicAdd(&lcur[b], 1);
        bucketed[slot] = (((unsigned int)(r & (RPB - 1))) << SBITS) | sv;
    }
}

// ---------------------------------------------------------------------------
// Kernel 5: fused per-bucket group + gather. One block per bucket.
// ---------------------------------------------------------------------------
__global__ __launch_bounds__(1024) void bucket_gather_kernel(
    const unsigned int* __restrict__ bucketed,
    const int* __restrict__ bbase, const int* __restrict__ bcur,
    const float* __restrict__ msg, float* __restrict__ agg)
{
    __shared__ unsigned int elds[CAP];
    __shared__ int dcnt[RPB];
    __shared__ int dcur[RPB];
    const int tid = threadIdx.x;
    const int b = blockIdx.x;
    const int gs = bbase[b];
    const int ge = bcur[b];
    const int nb = ge - gs;

    if (tid < RPB) dcnt[tid] = 0;
    __syncthreads();
    for (int i = tid; i < nb; i += 1024)
        atomicAdd(&dcnt[bucketed[gs + i] >> SBITS], 1);
    __syncthreads();
    if (tid < RPB) dcur[tid] = dcnt[tid];
    __syncthreads();
    #pragma unroll
    for (int off = 1; off < RPB; off <<= 1) {
        int t = 0;
        if (tid < RPB && tid >= off) t = dcur[tid - off];
        __syncthreads();
        if (tid < RPB) dcur[tid] += t;
        __syncthreads();
    }
    if (tid < RPB) dcur[tid] -= dcnt[tid];   // exclusive
    __syncthreads();
    for (int i = tid; i < nb; i += 1024) {
        const unsigned int v = bucketed[gs + i];
        const int rl = v >> SBITS;
        const int slot = atomicAdd(&dcur[rl], 1);
        if (slot < CAP) elds[slot] = v & SMASK;
    }
    __syncthreads();

    const int hw = tid >> 5;          // 0..31
    const int c = tid & 31;
    const bool act = c < ND;
    for (int rl = hw; rl < RPB; rl += 32) {
        int end = dcur[rl];
        const int cv = dcnt[rl];
        int st = end - cv;
        if (st < 0) st = 0;
        if (end > CAP) end = CAP;
        float a0 = 0.f, a1 = 0.f, a2 = 0.f, a3 = 0.f;
        int i = st;
        for (; i + 3 < end; i += 4) {
            const int s0 = elds[i + 0];
            const int s1 = elds[i + 1];
            const int s2 = elds[i + 2];
            const int s3 = elds[i + 3];
            if (act) {
                a0 += msg[s0 * ND + c];
                a1 += msg[s1 * ND + c];
                a2 += msg[s2 * ND + c];
                a3 += msg[s3 * ND + c];
            }
        }
        for (; i < end; i++) {
            const int s = elds[i];
            if (act) a0 += msg[s * ND + c];
        }
        if (act) agg[((size_t)b * RPB + rl) * ND + c] = (a0 + a1) + (a2 + a3);
    }
}

// ---------------------------------------------------------------------------
// Kernel 6: node output MLP (40 -> 64 -> 32 -> 20), 128 nodes per block.
// ---------------------------------------------------------------------------
__global__ __launch_bounds__(256) void node_mlp_kernel(
    const float* __restrict__ logits, const float* __restrict__ hidden,
    const float* __restrict__ agg,
    const float* __restrict__ W1, const float* __restrict__ b1,
    const float* __restrict__ W2, const float* __restrict__ b2,
    const float* __restrict__ W3, const float* __restrict__ b3,
    float* __restrict__ out)
{
    // region A: max(X 40*XS, H2 32*XS, Ol 128*20) = 40*XS floats
    __shared__ float regA[ND2 * XS];
    __shared__ float H1[64 * XS];
    __shared__ float sW1[ND2 * 64], sb1[64], sW2[64 * 32], sb2[32], sW3[32 * ND], sb3[ND];
    const int tid = threadIdx.x;
    const int nb0 = blockIdx.x * NPB;

    lds_fill(sW1, W1, ND2 * 64, tid, 256);
    lds_fill(sb1, b1, 64, tid, 256);
    lds_fill(sW2, W2, 64 * 32, tid, 256);
    lds_fill(sb2, b2, 32, tid, 256);
    lds_fill(sW3, W3, 32 * ND, tid, 256);
    lds_fill(sb3, b3, ND, tid, 256);

    float* Xl = regA;
    if (tid < NPB) {
        const float4 lv = reinterpret_cast<const float4*>(logits)[nb0 + tid];
        Xl[0 * XS + tid] = lv.x; Xl[1 * XS + tid] = lv.y;
        Xl[2 * XS + tid] = lv.z; Xl[3 * XS + tid] = lv.w;
    }
    #pragma unroll
    for (int u = 0; u < 2; u++) {
        const int idx = u * 256 + tid;
        const int n = idx >> 2, qq = idx & 3;
        const float4 hv = reinterpret_cast<const float4*>(hidden)[(size_t)(nb0 + n) * 4 + qq];
        Xl[(4 + qq * 4 + 0) * XS + n] = hv.x;
        Xl[(4 + qq * 4 + 1) * XS + n] = hv.y;
        Xl[(4 + qq * 4 + 2) * XS + n] = hv.z;
        Xl[(4 + qq * 4 + 3) * XS + n] = hv.w;
    }
    // agg -> rows 20..39 (128 nodes x 5 float4 = 640)
    for (int idx = tid; idx < NPB * 5; idx += 256) {
        const int n = idx / 5, qq = idx % 5;
        const float4 av = reinterpret_cast<const float4*>(agg)[(size_t)(nb0 + n) * 5 + qq];
        Xl[(ND + qq * 4 + 0) * XS + n] = av.x;
        Xl[(ND + qq * 4 + 1) * XS + n] = av.y;
        Xl[(ND + qq * 4 + 2) * XS + n] = av.z;
        Xl[(ND + qq * 4 + 3) * XS + n] = av.w;
    }
    __syncthreads();

    mlp3_core<ND2>(tid, Xl, H1, regA /*H2*/, regA /*Ol*/, sW1, sb1, sW2, sb2, sW3, sb3);

    // epilogue: split logits / hidden
    if (tid < NPB) {
        const float* orow = regA + tid * ND;
        reinterpret_cast<float4*>(out)[nb0 + tid] =
            make_float4(orow[0], orow[1], orow[2], orow[3]);
        float4* ho = reinterpret_cast<float4*>(out + (size_t)NN * NLOGIT + (size_t)(nb0 + tid) * NHID);
        #pragma unroll
        for (int k = 0; k < 4; k++)
            ho[k] = make_float4(orow[4 + k*4 + 0], orow[4 + k*4 + 1],
                                orow[4 + k*4 + 2], orow[4 + k*4 + 3]);
    }
}

extern "C" void kernel_launch(void* const* d_in, const int* in_sizes, int n_in,
                              void* d_out, int out_size, void* d_ws, size_t ws_size,
                              hipStream_t stream) {
    const float* logits   = (const float*)d_in[0];
    const float* hidden   = (const float*)d_in[1];
    const int*   senders  = (const int*)d_in[2];
    const int*   receivers= (const int*)d_in[3];
    const float* We1 = (const float*)d_in[4];
    const float* be1 = (const float*)d_in[5];
    const float* We2 = (const float*)d_in[6];
    const float* be2 = (const float*)d_in[7];
    const float* We3 = (const float*)d_in[8];
    const float* be3 = (const float*)d_in[9];
    const float* Wn1 = (const float*)d_in[10];
    const float* bn1 = (const float*)d_in[11];
    const float* Wn2 = (const float*)d_in[12];
    const float* bn2 = (const float*)d_in[13];
    const float* Wn3 = (const float*)d_in[14];
    const float* bn3 = (const float*)d_in[15];
    float* out = (float*)d_out;

    // Workspace layout (~58.8 MB)
    float* msg = (float*)d_ws;                         // NN*ND floats (21 MB)
    float* agg = msg + (size_t)NN * ND;                // NN*ND floats (21 MB)
    unsigned int* bucketed = (unsigned int*)(agg + (size_t)NN * ND);  // NE u32 (16.8 MB)
    int* bcnt  = (int*)(bucketed + NE);                // NBUCK ints
    int* bbase = bcnt + NBUCK;                         // NBUCK ints
    int* bcur  = bbase + NBUCK;                        // NBUCK ints

    msg_mlp_kernel<<<NN / NPB, 256, 0, stream>>>(
        logits, hidden, We1, be1, We2, be2, We3, be3, msg, bcnt);
    bucket_hist_kernel<<<FBLK, 256, 0, stream>>>(receivers, bcnt);
    bucket_scan_kernel<<<1, NBUCK, 0, stream>>>(bcnt, bbase, bcur);
    bucket_fill_kernel<<<FBLK, 256, 0, stream>>>(senders, receivers, bcur, bucketed);
    bucket_gather_kernel<<<NBUCK, 1024, 0, stream>>>(bucketed, bbase, bcur, msg, agg);
    node_mlp_kernel<<<NN / NPB, 256, 0, stream>>>(
        logits, hidden, agg, Wn1, bn1, Wn2, bn2, Wn3, bn3, out);
}

// Round 5
// 270.064 us; speedup vs baseline: 16.2768x; 1.0991x over previous
//
#include <hip/hip_runtime.h>
#include <hip/hip_fp16.h>

#define NN 262144
#define NE 4194304
#define NLOGIT 4
#define NHID 16
#define ND 20   // NLOGIT + NHID
#define ND2 40  // 2*ND

#define NBUCK 512          // buckets
#define BSHIFT 9           // bucket = receiver >> BSHIFT
#define RPB 512            // receivers per bucket (NN / NBUCK)
#define SBITS 18           // sender id bits (NN = 2^18)
#define SMASK ((1u << SBITS) - 1)
#define FBLK 1024          // blocks in hist/fill
#define EPB (NE / FBLK)    // 4096 edges per block
#define EPT (EPB / 256)    // 16 edges per thread
#define CAP 9728           // per-bucket LDS edge capacity (mean 8192, +17 sigma)

#define NPB 128            // nodes per MLP block
#define XS 132             // padded LDS column stride (132 % 32 = 4 -> de-conflicted)

#define MROW 16            // msg row = 16 uint32 = 32 halfs = 64 B (one cache line)

__device__ __forceinline__ void lds_fill(float* dst, const float* src, int n, int tid, int nthreads) {
    for (int i = tid; i < n; i += nthreads) dst[i] = src[i];
}

// ---------------------------------------------------------------------------
// Register-blocked 3-layer MLP core over a 128-node LDS tile.
// Thread t: node quad q = t&31 (nodes q*4..q*4+3), feature group g = t>>5.
// Xl: [IN][XS] transposed input. H1: [64][XS]. H2: [32][XS] (may alias Xl).
// Ol: [NPB][20] output staging (may alias H2 region). Barriers inside.
// ---------------------------------------------------------------------------
template<int IN>
__device__ __forceinline__ void mlp3_core(
    const int tid, const float* Xl, float* H1, float* H2, float* Ol,
    const float* sW1, const float* sb1,
    const float* sW2, const float* sb2,
    const float* sW3, const float* sb3)
{
    const int q = tid & 31;
    const int g = tid >> 5;
    const int n0 = q * 4;

    // ---- layer 1: IN -> 64, feats g*8 .. g*8+7, nodes n0..n0+3
    float a1[8][4];
    #pragma unroll
    for (int f = 0; f < 8; f++) {
        const float b = sb1[g * 8 + f];
        a1[f][0] = b; a1[f][1] = b; a1[f][2] = b; a1[f][3] = b;
    }
    #pragma unroll
    for (int i = 0; i < IN; i++) {
        const float4 xv = *reinterpret_cast<const float4*>(&Xl[i * XS + n0]);
        const float4 w0 = *reinterpret_cast<const float4*>(&sW1[i * 64 + g * 8]);
        const float4 w1 = *reinterpret_cast<const float4*>(&sW1[i * 64 + g * 8 + 4]);
        const float wf[8] = {w0.x, w0.y, w0.z, w0.w, w1.x, w1.y, w1.z, w1.w};
        #pragma unroll
        for (int f = 0; f < 8; f++) {
            a1[f][0] = fmaf(xv.x, wf[f], a1[f][0]);
            a1[f][1] = fmaf(xv.y, wf[f], a1[f][1]);
            a1[f][2] = fmaf(xv.z, wf[f], a1[f][2]);
            a1[f][3] = fmaf(xv.w, wf[f], a1[f][3]);
        }
    }
    #pragma unroll
    for (int f = 0; f < 8; f++) {
        float4 v = make_float4(fmaxf(a1[f][0], 0.f), fmaxf(a1[f][1], 0.f),
                               fmaxf(a1[f][2], 0.f), fmaxf(a1[f][3], 0.f));
        *reinterpret_cast<float4*>(&H1[(g * 8 + f) * XS + n0]) = v;
    }
    __syncthreads();   // H1 complete; Xl dead from here (H2 may alias it)

    // ---- layer 2: 64 -> 32, feats g*4 .. g*4+3
    float a2[4][4];
    #pragma unroll
    for (int f = 0; f < 4; f++) {
        const float b = sb2[g * 4 + f];
        a2[f][0] = b; a2[f][1] = b; a2[f][2] = b; a2[f][3] = b;
    }
    #pragma unroll
    for (int i = 0; i < 64; i++) {
        const float4 xv = *reinterpret_cast<const float4*>(&H1[i * XS + n0]);
        const float4 w = *reinterpret_cast<const float4*>(&sW2[i * 32 + g * 4]);
        const float wf[4] = {w.x, w.y, w.z, w.w};
        #pragma unroll
        for (int f = 0; f < 4; f++) {
            a2[f][0] = fmaf(xv.x, wf[f], a2[f][0]);
            a2[f][1] = fmaf(xv.y, wf[f], a2[f][1]);
            a2[f][2] = fmaf(xv.z, wf[f], a2[f][2]);
            a2[f][3] = fmaf(xv.w, wf[f], a2[f][3]);
        }
    }
    #pragma unroll
    for (int f = 0; f < 4; f++) {
        float4 v = make_float4(fmaxf(a2[f][0], 0.f), fmaxf(a2[f][1], 0.f),
                               fmaxf(a2[f][2], 0.f), fmaxf(a2[f][3], 0.f));
        *reinterpret_cast<float4*>(&H2[(g * 4 + f) * XS + n0]) = v;
    }
    __syncthreads();   // H2 complete

    // ---- layer 3: 32 -> 20, groups 0..4 active, feats g*4 .. g*4+3
    float a3[4][4];
    if (g < 5) {
        #pragma unroll
        for (int f = 0; f < 4; f++) {
            const float b = sb3[g * 4 + f];
            a3[f][0] = b; a3[f][1] = b; a3[f][2] = b; a3[f][3] = b;
        }
        #pragma unroll
        for (int i = 0; i < 32; i++) {
            const float4 xv = *reinterpret_cast<const float4*>(&H2[i * XS + n0]);
            const float4 w = *reinterpret_cast<const float4*>(&sW3[i * 20 + g * 4]);
            const float wf[4] = {w.x, w.y, w.z, w.w};
            #pragma unroll
            for (int f = 0; f < 4; f++) {
                a3[f][0] = fmaf(xv.x, wf[f], a3[f][0]);
                a3[f][1] = fmaf(xv.y, wf[f], a3[f][1]);
                a3[f][2] = fmaf(xv.z, wf[f], a3[f][2]);
                a3[f][3] = fmaf(xv.w, wf[f], a3[f][3]);
            }
        }
    }
    __syncthreads();   // all H2 reads done; Ol may alias H2
    if (g < 5) {
        #pragma unroll
        for (int f = 0; f < 4; f++) {
            #pragma unroll
            for (int k = 0; k < 4; k++)
                Ol[(n0 + k) * ND + g * 4 + f] = a3[f][k];
        }
    }
    __syncthreads();   // Ol ready for epilogue
}

// ---------------------------------------------------------------------------
// Kernel 1: edge-message MLP (20 -> 64 -> 32 -> 20), 128 nodes per block.
// Output: fp16-packed msg rows, 32 half slots (64 B, one line) per node.
// Block 0 zeroes bcnt.
// ---------------------------------------------------------------------------
__global__ __launch_bounds__(256) void msg_mlp_kernel(
    const float* __restrict__ logits, const float* __restrict__ hidden,
    const float* __restrict__ W1, const float* __restrict__ b1,
    const float* __restrict__ W2, const float* __restrict__ b2,
    const float* __restrict__ W3, const float* __restrict__ b3,
    unsigned int* __restrict__ msgh, int* __restrict__ bcnt)
{
    // region A: max(X 20*XS, H2 32*XS, Ol 128*20) = 32*XS floats
    __shared__ float regA[32 * XS];
    __shared__ float H1[64 * XS];
    __shared__ float sW1[ND * 64], sb1[64], sW2[64 * 32], sb2[32], sW3[32 * ND], sb3[ND];
    const int tid = threadIdx.x;
    const int nb0 = blockIdx.x * NPB;

    if (blockIdx.x == 0) { bcnt[tid] = 0; bcnt[256 + tid] = 0; }

    lds_fill(sW1, W1, ND * 64, tid, 256);
    lds_fill(sb1, b1, 64, tid, 256);
    lds_fill(sW2, W2, 64 * 32, tid, 256);
    lds_fill(sb2, b2, 32, tid, 256);
    lds_fill(sW3, W3, 32 * ND, tid, 256);
    lds_fill(sb3, b3, ND, tid, 256);

    float* Xl = regA;
    // stage logits -> rows 0..3
    if (tid < NPB) {
        const float4 lv = reinterpret_cast<const float4*>(logits)[nb0 + tid];
        Xl[0 * XS + tid] = lv.x; Xl[1 * XS + tid] = lv.y;
        Xl[2 * XS + tid] = lv.z; Xl[3 * XS + tid] = lv.w;
    }
    // stage hidden -> rows 4..19 (128 nodes x 4 float4 = 512)
    #pragma unroll
    for (int u = 0; u < 2; u++) {
        const int idx = u * 256 + tid;
        const int n = idx >> 2, qq = idx & 3;
        const float4 hv = reinterpret_cast<const float4*>(hidden)[(size_t)(nb0 + n) * 4 + qq];
        Xl[(4 + qq * 4 + 0) * XS + n] = hv.x;
        Xl[(4 + qq * 4 + 1) * XS + n] = hv.y;
        Xl[(4 + qq * 4 + 2) * XS + n] = hv.z;
        Xl[(4 + qq * 4 + 3) * XS + n] = hv.w;
    }
    __syncthreads();

    mlp3_core<ND>(tid, Xl, H1, regA /*H2*/, regA /*Ol*/, sW1, sb1, sW2, sb2, sW3, sb3);

    // epilogue: pack fp16 rows. NPB nodes x 16 uint32 = 2048 words.
    unsigned int* mo = msgh + (size_t)nb0 * MROW;
    #pragma unroll
    for (int idx = tid; idx < NPB * MROW; idx += 256) {
        const int n = idx >> 4, slot = idx & 15;
        const int c = slot * 2;
        float v0 = 0.f, v1 = 0.f;
        if (c < ND) { v0 = regA[n * ND + c]; v1 = regA[n * ND + c + 1]; }
        __half2 h = __floats2half2_rn(v0, v1);
        mo[idx] = *reinterpret_cast<unsigned int*>(&h);
    }
}

// ---------------------------------------------------------------------------
// Kernel 2: bucket histogram. LDS-aggregated; 512 global atomics per 4096 edges.
// ---------------------------------------------------------------------------
__global__ __launch_bounds__(256) void bucket_hist_kernel(
    const int* __restrict__ receivers, int* __restrict__ bcnt)
{
    __shared__ int cnt[NBUCK];
    const int tid = threadIdx.x;
    cnt[tid] = 0; cnt[256 + tid] = 0;
    __syncthreads();
    const int base = blockIdx.x * EPB;
    #pragma unroll
    for (int k = 0; k < EPT; k++) {
        const int r = receivers[base + k * 256 + tid];
        atomicAdd(&cnt[r >> BSHIFT], 1);
    }
    __syncthreads();
    #pragma unroll
    for (int j = tid; j < NBUCK; j += 256)
        if (cnt[j] > 0) atomicAdd(&bcnt[j], cnt[j]);
}

// ---------------------------------------------------------------------------
// Kernel 3: exclusive scan of bcnt -> bbase, bcur. One block.
// ---------------------------------------------------------------------------
__global__ __launch_bounds__(NBUCK) void bucket_scan_kernel(
    const int* __restrict__ bcnt, int* __restrict__ bbase, int* __restrict__ bcur)
{
    __shared__ int s[NBUCK];
    const int tid = threadIdx.x;
    const int v = bcnt[tid];
    s[tid] = v;
    __syncthreads();
    #pragma unroll
    for (int off = 1; off < NBUCK; off <<= 1) {
        int t = (tid >= off) ? s[tid - off] : 0;
        __syncthreads();
        s[tid] += t;
        __syncthreads();
    }
    const int ex = s[tid] - v;
    bbase[tid] = ex;
    bcur[tid] = ex;
}

// ---------------------------------------------------------------------------
// Kernel 4: bucket fill. Per-block LDS histogram + one global reservation per
// (block,bucket). Entry: (rlocal << 18) | sender.
// ---------------------------------------------------------------------------
__global__ __launch_bounds__(256) void bucket_fill_kernel(
    const int* __restrict__ senders, const int* __restrict__ receivers,
    int* __restrict__ bcur, unsigned int* __restrict__ bucketed)
{
    __shared__ int cnt[NBUCK];
    __shared__ int lcur[NBUCK];
    const int tid = threadIdx.x;
    cnt[tid] = 0; cnt[256 + tid] = 0;
    __syncthreads();
    const int base = blockIdx.x * EPB;
    #pragma unroll
    for (int k = 0; k < EPT; k++) {
        const int r = receivers[base + k * 256 + tid];
        atomicAdd(&cnt[r >> BSHIFT], 1);
    }
    __syncthreads();
    #pragma unroll
    for (int j = tid; j < NBUCK; j += 256) {
        const int c = cnt[j];
        lcur[j] = (c > 0) ? atomicAdd(&bcur[j], c) : 0;
    }
    __syncthreads();
    #pragma unroll
    for (int k = 0; k < EPT; k++) {
        const int idx = base + k * 256 + tid;
        const int r = receivers[idx];
        const unsigned int sv = (unsigned int)senders[idx];
        const int b = r >> BSHIFT;
        const int slot = atomicAdd(&lcur[b], 1);
        bucketed[slot] = (((unsigned int)(r & (RPB - 1))) << SBITS) | sv;
    }
}

// ---------------------------------------------------------------------------
// Kernel 5: fused per-bucket group + gather. One block per bucket.
// Gather reads one 64 B fp16 line per edge; lane c<10 handles comps 2c,2c+1.
// ---------------------------------------------------------------------------
__global__ __launch_bounds__(1024) void bucket_gather_kernel(
    const unsigned int* __restrict__ bucketed,
    const int* __restrict__ bbase, const int* __restrict__ bcur,
    const unsigned int* __restrict__ msgh, float* __restrict__ agg)
{
    __shared__ unsigned int elds[CAP];
    __shared__ int dcnt[RPB];
    __shared__ int dcur[RPB];
    const int tid = threadIdx.x;
    const int b = blockIdx.x;
    const int gs = bbase[b];
    const int ge = bcur[b];
    const int nb = ge - gs;

    if (tid < RPB) dcnt[tid] = 0;
    __syncthreads();
    for (int i = tid; i < nb; i += 1024)
        atomicAdd(&dcnt[bucketed[gs + i] >> SBITS], 1);
    __syncthreads();
    if (tid < RPB) dcur[tid] = dcnt[tid];
    __syncthreads();
    #pragma unroll
    for (int off = 1; off < RPB; off <<= 1) {
        int t = 0;
        if (tid < RPB && tid >= off) t = dcur[tid - off];
        __syncthreads();
        if (tid < RPB) dcur[tid] += t;
        __syncthreads();
    }
    if (tid < RPB) dcur[tid] -= dcnt[tid];   // exclusive
    __syncthreads();
    for (int i = tid; i < nb; i += 1024) {
        const unsigned int v = bucketed[gs + i];
        const int rl = v >> SBITS;
        const int slot = atomicAdd(&dcur[rl], 1);
        if (slot < CAP) elds[slot] = v & SMASK;
    }
    __syncthreads();

    const int hw = tid >> 5;          // 0..31
    const int c = tid & 31;
    const bool act = c < ND / 2;      // lanes 0..9: components 2c, 2c+1
    for (int rl = hw; rl < RPB; rl += 32) {
        int end = dcur[rl];
        const int cv = dcnt[rl];
        int st = end - cv;
        if (st < 0) st = 0;
        if (end > CAP) end = CAP;
        float a00 = 0.f, a01 = 0.f, a10 = 0.f, a11 = 0.f;
        float a20 = 0.f, a21 = 0.f, a30 = 0.f, a31 = 0.f;
        int i = st;
        for (; i + 3 < end; i += 4) {
            const int s0 = elds[i + 0];
            const int s1 = elds[i + 1];
            const int s2 = elds[i + 2];
            const int s3 = elds[i + 3];
            if (act) {
                const unsigned int w0 = msgh[s0 * MROW + c];
                const unsigned int w1 = msgh[s1 * MROW + c];
                const unsigned int w2 = msgh[s2 * MROW + c];
                const unsigned int w3 = msgh[s3 * MROW + c];
                const float2 f0 = __half22float2(*reinterpret_cast<const __half2*>(&w0));
                const float2 f1 = __half22float2(*reinterpret_cast<const __half2*>(&w1));
                const float2 f2 = __half22float2(*reinterpret_cast<const __half2*>(&w2));
                const float2 f3 = __half22float2(*reinterpret_cast<const __half2*>(&w3));
                a00 += f0.x; a01 += f0.y;
                a10 += f1.x; a11 += f1.y;
                a20 += f2.x; a21 += f2.y;
                a30 += f3.x; a31 += f3.y;
            }
        }
        for (; i < end; i++) {
            const int s = elds[i];
            if (act) {
                const unsigned int w = msgh[s * MROW + c];
                const float2 f = __half22float2(*reinterpret_cast<const __half2*>(&w));
                a00 += f.x; a01 += f.y;
            }
        }
        if (act) {
            float2 r = make_float2((a00 + a10) + (a20 + a30),
                                   (a01 + a11) + (a21 + a31));
            *reinterpret_cast<float2*>(&agg[((size_t)b * RPB + rl) * ND + 2 * c]) = r;
        }
    }
}

// ---------------------------------------------------------------------------
// Kernel 6: node output MLP (40 -> 64 -> 32 -> 20), 128 nodes per block.
// ---------------------------------------------------------------------------
__global__ __launch_bounds__(256) void node_mlp_kernel(
    const float* __restrict__ logits, const float* __restrict__ hidden,
    const float* __restrict__ agg,
    const float* __restrict__ W1, const float* __restrict__ b1,
    const float* __restrict__ W2, const float* __restrict__ b2,
    const float* __restrict__ W3, const float* __restrict__ b3,
    float* __restrict__ out)
{
    // region A: max(X 40*XS, H2 32*XS, Ol 128*20) = 40*XS floats
    __shared__ float regA[ND2 * XS];
    __shared__ float H1[64 * XS];
    __shared__ float sW1[ND2 * 64], sb1[64], sW2[64 * 32], sb2[32], sW3[32 * ND], sb3[ND];
    const int tid = threadIdx.x;
    const int nb0 = blockIdx.x * NPB;

    lds_fill(sW1, W1, ND2 * 64, tid, 256);
    lds_fill(sb1, b1, 64, tid, 256);
    lds_fill(sW2, W2, 64 * 32, tid, 256);
    lds_fill(sb2, b2, 32, tid, 256);
    lds_fill(sW3, W3, 32 * ND, tid, 256);
    lds_fill(sb3, b3, ND, tid, 256);

    float* Xl = regA;
    if (tid < NPB) {
        const float4 lv = reinterpret_cast<const float4*>(logits)[nb0 + tid];
        Xl[0 * XS + tid] = lv.x; Xl[1 * XS + tid] = lv.y;
        Xl[2 * XS + tid] = lv.z; Xl[3 * XS + tid] = lv.w;
    }
    #pragma unroll
    for (int u = 0; u < 2; u++) {
        const int idx = u * 256 + tid;
        const int n = idx >> 2, qq = idx & 3;
        const float4 hv = reinterpret_cast<const float4*>(hidden)[(size_t)(nb0 + n) * 4 + qq];
        Xl[(4 + qq * 4 + 0) * XS + n] = hv.x;
        Xl[(4 + qq * 4 + 1) * XS + n] = hv.y;
        Xl[(4 + qq * 4 + 2) * XS + n] = hv.z;
        Xl[(4 + qq * 4 + 3) * XS + n] = hv.w;
    }
    // agg -> rows 20..39 (128 nodes x 5 float4 = 640)
    for (int idx = tid; idx < NPB * 5; idx += 256) {
        const int n = idx / 5, qq = idx % 5;
        const float4 av = reinterpret_cast<const float4*>(agg)[(size_t)(nb0 + n) * 5 + qq];
        Xl[(ND + qq * 4 + 0) * XS + n] = av.x;
        Xl[(ND + qq * 4 + 1) * XS + n] = av.y;
        Xl[(ND + qq * 4 + 2) * XS + n] = av.z;
        Xl[(ND + qq * 4 + 3) * XS + n] = av.w;
    }
    __syncthreads();

    mlp3_core<ND2>(tid, Xl, H1, regA /*H2*/, regA /*Ol*/, sW1, sb1, sW2, sb2, sW3, sb3);

    // epilogue: split logits / hidden
    if (tid < NPB) {
        const float* orow = regA + tid * ND;
        reinterpret_cast<float4*>(out)[nb0 + tid] =
            make_float4(orow[0], orow[1], orow[2], orow[3]);
        float4* ho = reinterpret_cast<float4*>(out + (size_t)NN * NLOGIT + (size_t)(nb0 + tid) * NHID);
        #pragma unroll
        for (int k = 0; k < 4; k++)
            ho[k] = make_float4(orow[4 + k*4 + 0], orow[4 + k*4 + 1],
                                orow[4 + k*4 + 2], orow[4 + k*4 + 3]);
    }
}

extern "C" void kernel_launch(void* const* d_in, const int* in_sizes, int n_in,
                              void* d_out, int out_size, void* d_ws, size_t ws_size,
                              hipStream_t stream) {
    const float* logits   = (const float*)d_in[0];
    const float* hidden   = (const float*)d_in[1];
    const int*   senders  = (const int*)d_in[2];
    const int*   receivers= (const int*)d_in[3];
    const float* We1 = (const float*)d_in[4];
    const float* be1 = (const float*)d_in[5];
    const float* We2 = (const float*)d_in[6];
    const float* be2 = (const float*)d_in[7];
    const float* We3 = (const float*)d_in[8];
    const float* be3 = (const float*)d_in[9];
    const float* Wn1 = (const float*)d_in[10];
    const float* bn1 = (const float*)d_in[11];
    const float* Wn2 = (const float*)d_in[12];
    const float* bn2 = (const float*)d_in[13];
    const float* Wn3 = (const float*)d_in[14];
    const float* bn3 = (const float*)d_in[15];
    float* out = (float*)d_out;

    // Workspace layout (~55 MB)
    unsigned int* msgh = (unsigned int*)d_ws;          // NN*MROW u32 (16.8 MB, 64B rows)
    float* agg = (float*)(msgh + (size_t)NN * MROW);   // NN*ND floats (21 MB)
    unsigned int* bucketed = (unsigned int*)(agg + (size_t)NN * ND);  // NE u32 (16.8 MB)
    int* bcnt  = (int*)(bucketed + NE);                // NBUCK ints
    int* bbase = bcnt + NBUCK;                         // NBUCK ints
    int* bcur  = bbase + NBUCK;                        // NBUCK ints

    msg_mlp_kernel<<<NN / NPB, 256, 0, stream>>>(
        logits, hidden, We1, be1, We2, be2, We3, be3, msgh, bcnt);
    bucket_hist_kernel<<<FBLK, 256, 0, stream>>>(receivers, bcnt);
    bucket_scan_kernel<<<1, NBUCK, 0, stream>>>(bcnt, bbase, bcur);
    bucket_fill_kernel<<<FBLK, 256, 0, stream>>>(senders, receivers, bcur, bucketed);
    bucket_gather_kernel<<<NBUCK, 1024, 0, stream>>>(bucketed, bbase, bcur, msgh, agg);
    node_mlp_kernel<<<NN / NPB, 256, 0, stream>>>(
        logits, hidden, agg, Wn1, bn1, Wn2, bn2, Wn3, bn3, out);
}

// Round 6
// 238.617 us; speedup vs baseline: 18.4219x; 1.1318x over previous
//
#include <hip/hip_runtime.h>
#include <hip/hip_fp16.h>

#define NN 262144
#define NE 4194304
#define NLOGIT 4
#define NHID 16
#define ND 20   // NLOGIT + NHID
#define ND2 40  // 2*ND

#define NBUCK 512          // buckets
#define BSHIFT 9           // bucket = receiver >> BSHIFT
#define RPB 512            // receivers per bucket (NN / NBUCK)
#define SBITS 18           // sender id bits (NN = 2^18)
#define SMASK ((1u << SBITS) - 1)
#define FBLK 1024          // fill blocks (== gather block's thread count)
#define EPB (NE / FBLK)    // 4096 edges per fill block
#define EPT (EPB / 256)    // 16 edges per thread
#define CAP 9728           // per-bucket LDS edge capacity (mean 8192, +17 sigma)

#define NPB 128            // nodes per MLP block
#define XS 132             // padded LDS column stride

#define MROW 16            // msg row = 16 uint32 = 32 halfs = 64 B (one cache line)

__device__ __forceinline__ void lds_fill(float* dst, const float* src, int n, int tid, int nthreads) {
    for (int i = tid; i < n; i += nthreads) dst[i] = src[i];
}

// ---------------------------------------------------------------------------
// Register-blocked 3-layer MLP core over a 128-node LDS tile.
// Thread t: node quad q = t&31 (nodes q*4..q*4+3), feature group g = t>>5.
// Xl: [IN][XS] transposed input. H1: [64][XS]. H2: [32][XS] (may alias Xl).
// Ol: [NPB][20] output staging (may alias H2 region). Barriers inside.
// ---------------------------------------------------------------------------
template<int IN>
__device__ __forceinline__ void mlp3_core(
    const int tid, const float* Xl, float* H1, float* H2, float* Ol,
    const float* sW1, const float* sb1,
    const float* sW2, const float* sb2,
    const float* sW3, const float* sb3)
{
    const int q = tid & 31;
    const int g = tid >> 5;
    const int n0 = q * 4;

    // ---- layer 1: IN -> 64, feats g*8 .. g*8+7, nodes n0..n0+3
    float a1[8][4];
    #pragma unroll
    for (int f = 0; f < 8; f++) {
        const float b = sb1[g * 8 + f];
        a1[f][0] = b; a1[f][1] = b; a1[f][2] = b; a1[f][3] = b;
    }
    #pragma unroll
    for (int i = 0; i < IN; i++) {
        const float4 xv = *reinterpret_cast<const float4*>(&Xl[i * XS + n0]);
        const float4 w0 = *reinterpret_cast<const float4*>(&sW1[i * 64 + g * 8]);
        const float4 w1 = *reinterpret_cast<const float4*>(&sW1[i * 64 + g * 8 + 4]);
        const float wf[8] = {w0.x, w0.y, w0.z, w0.w, w1.x, w1.y, w1.z, w1.w};
        #pragma unroll
        for (int f = 0; f < 8; f++) {
            a1[f][0] = fmaf(xv.x, wf[f], a1[f][0]);
            a1[f][1] = fmaf(xv.y, wf[f], a1[f][1]);
            a1[f][2] = fmaf(xv.z, wf[f], a1[f][2]);
            a1[f][3] = fmaf(xv.w, wf[f], a1[f][3]);
        }
    }
    #pragma unroll
    for (int f = 0; f < 8; f++) {
        float4 v = make_float4(fmaxf(a1[f][0], 0.f), fmaxf(a1[f][1], 0.f),
                               fmaxf(a1[f][2], 0.f), fmaxf(a1[f][3], 0.f));
        *reinterpret_cast<float4*>(&H1[(g * 8 + f) * XS + n0]) = v;
    }
    __syncthreads();   // H1 complete; Xl dead from here (H2 may alias it)

    // ---- layer 2: 64 -> 32, feats g*4 .. g*4+3
    float a2[4][4];
    #pragma unroll
    for (int f = 0; f < 4; f++) {
        const float b = sb2[g * 4 + f];
        a2[f][0] = b; a2[f][1] = b; a2[f][2] = b; a2[f][3] = b;
    }
    #pragma unroll
    for (int i = 0; i < 64; i++) {
        const float4 xv = *reinterpret_cast<const float4*>(&H1[i * XS + n0]);
        const float4 w = *reinterpret_cast<const float4*>(&sW2[i * 32 + g * 4]);
        const float wf[4] = {w.x, w.y, w.z, w.w};
        #pragma unroll
        for (int f = 0; f < 4; f++) {
            a2[f][0] = fmaf(xv.x, wf[f], a2[f][0]);
            a2[f][1] = fmaf(xv.y, wf[f], a2[f][1]);
            a2[f][2] = fmaf(xv.z, wf[f], a2[f][2]);
            a2[f][3] = fmaf(xv.w, wf[f], a2[f][3]);
        }
    }
    #pragma unroll
    for (int f = 0; f < 4; f++) {
        float4 v = make_float4(fmaxf(a2[f][0], 0.f), fmaxf(a2[f][1], 0.f),
                               fmaxf(a2[f][2], 0.f), fmaxf(a2[f][3], 0.f));
        *reinterpret_cast<float4*>(&H2[(g * 4 + f) * XS + n0]) = v;
    }
    __syncthreads();   // H2 complete

    // ---- layer 3: 32 -> 20, groups 0..4 active, feats g*4 .. g*4+3
    float a3[4][4];
    if (g < 5) {
        #pragma unroll
        for (int f = 0; f < 4; f++) {
            const float b = sb3[g * 4 + f];
            a3[f][0] = b; a3[f][1] = b; a3[f][2] = b; a3[f][3] = b;
        }
        #pragma unroll
        for (int i = 0; i < 32; i++) {
            const float4 xv = *reinterpret_cast<const float4*>(&H2[i * XS + n0]);
            const float4 w = *reinterpret_cast<const float4*>(&sW3[i * 20 + g * 4]);
            const float wf[4] = {w.x, w.y, w.z, w.w};
            #pragma unroll
            for (int f = 0; f < 4; f++) {
                a3[f][0] = fmaf(xv.x, wf[f], a3[f][0]);
                a3[f][1] = fmaf(xv.y, wf[f], a3[f][1]);
                a3[f][2] = fmaf(xv.z, wf[f], a3[f][2]);
                a3[f][3] = fmaf(xv.w, wf[f], a3[f][3]);
            }
        }
    }
    __syncthreads();   // all H2 reads done; Ol may alias H2
    if (g < 5) {
        #pragma unroll
        for (int f = 0; f < 4; f++) {
            #pragma unroll
            for (int k = 0; k < 4; k++)
                Ol[(n0 + k) * ND + g * 4 + f] = a3[f][k];
        }
    }
    __syncthreads();   // Ol ready for epilogue
}

// ---------------------------------------------------------------------------
// Kernel 1: edge-message MLP (20 -> 64 -> 32 -> 20), 128 nodes per block.
// Output: fp16-packed msg rows, 32 half slots (64 B, one line) per node.
// ---------------------------------------------------------------------------
__global__ __launch_bounds__(256) void msg_mlp_kernel(
    const float* __restrict__ logits, const float* __restrict__ hidden,
    const float* __restrict__ W1, const float* __restrict__ b1,
    const float* __restrict__ W2, const float* __restrict__ b2,
    const float* __restrict__ W3, const float* __restrict__ b3,
    unsigned int* __restrict__ msgh)
{
    // region A: max(X 20*XS, H2 32*XS, Ol 128*20) = 32*XS floats
    __shared__ float regA[32 * XS];
    __shared__ float H1[64 * XS];
    __shared__ float sW1[ND * 64], sb1[64], sW2[64 * 32], sb2[32], sW3[32 * ND], sb3[ND];
    const int tid = threadIdx.x;
    const int nb0 = blockIdx.x * NPB;

    lds_fill(sW1, W1, ND * 64, tid, 256);
    lds_fill(sb1, b1, 64, tid, 256);
    lds_fill(sW2, W2, 64 * 32, tid, 256);
    lds_fill(sb2, b2, 32, tid, 256);
    lds_fill(sW3, W3, 32 * ND, tid, 256);
    lds_fill(sb3, b3, ND, tid, 256);

    float* Xl = regA;
    // stage logits -> rows 0..3
    if (tid < NPB) {
        const float4 lv = reinterpret_cast<const float4*>(logits)[nb0 + tid];
        Xl[0 * XS + tid] = lv.x; Xl[1 * XS + tid] = lv.y;
        Xl[2 * XS + tid] = lv.z; Xl[3 * XS + tid] = lv.w;
    }
    // stage hidden -> rows 4..19 (128 nodes x 4 float4 = 512)
    #pragma unroll
    for (int u = 0; u < 2; u++) {
        const int idx = u * 256 + tid;
        const int n = idx >> 2, qq = idx & 3;
        const float4 hv = reinterpret_cast<const float4*>(hidden)[(size_t)(nb0 + n) * 4 + qq];
        Xl[(4 + qq * 4 + 0) * XS + n] = hv.x;
        Xl[(4 + qq * 4 + 1) * XS + n] = hv.y;
        Xl[(4 + qq * 4 + 2) * XS + n] = hv.z;
        Xl[(4 + qq * 4 + 3) * XS + n] = hv.w;
    }
    __syncthreads();

    mlp3_core<ND>(tid, Xl, H1, regA /*H2*/, regA /*Ol*/, sW1, sb1, sW2, sb2, sW3, sb3);

    // epilogue: pack fp16 rows. NPB nodes x 16 uint32 = 2048 words.
    unsigned int* mo = msgh + (size_t)nb0 * MROW;
    #pragma unroll
    for (int idx = tid; idx < NPB * MROW; idx += 256) {
        const int n = idx >> 4, slot = idx & 15;
        const int c = slot * 2;
        float v0 = 0.f, v1 = 0.f;
        if (c < ND) { v0 = regA[n * ND + c]; v1 = regA[n * ND + c + 1]; }
        __half2 h = __floats2half2_rn(v0, v1);
        mo[idx] = *reinterpret_cast<unsigned int*>(&h);
    }
}

// ---------------------------------------------------------------------------
// Kernel 2: bucket fill (block-major). Each block counting-sorts its 4096
// edges by bucket in LDS and writes ONE contiguous coalesced 16 KB run.
// No global atomics. Per-(block,bucket) (off<<16)|cnt goes to tab (coalesced).
// ---------------------------------------------------------------------------
__global__ __launch_bounds__(256) void bucket_fill_kernel(
    const int* __restrict__ senders, const int* __restrict__ receivers,
    unsigned int* __restrict__ bucketed, unsigned int* __restrict__ tab)
{
    __shared__ int cnt[NBUCK];
    __shared__ int boff[NBUCK];
    __shared__ int lcur[NBUCK];
    __shared__ int psum[256];
    __shared__ unsigned int sorted[EPB];   // 16 KB
    const int tid = threadIdx.x;
    const int blk = blockIdx.x;

    cnt[tid] = 0; cnt[256 + tid] = 0;
    __syncthreads();

    int rr[EPT], ss[EPT];
    const int base = blk * EPB;
    #pragma unroll
    for (int k = 0; k < EPT; k++) {
        rr[k] = receivers[base + k * 256 + tid];
        ss[k] = senders[base + k * 256 + tid];
        atomicAdd(&cnt[rr[k] >> BSHIFT], 1);
    }
    __syncthreads();

    // exclusive scan over 512 buckets (pairs per thread + Hillis-Steele 256)
    const int c0 = cnt[2 * tid], c1 = cnt[2 * tid + 1];
    psum[tid] = c0 + c1;
    __syncthreads();
    #pragma unroll
    for (int off = 1; off < 256; off <<= 1) {
        int t = (tid >= off) ? psum[tid - off] : 0;
        __syncthreads();
        psum[tid] += t;
        __syncthreads();
    }
    const int ex = psum[tid] - (c0 + c1);
    boff[2 * tid] = ex;       boff[2 * tid + 1] = ex + c0;
    lcur[2 * tid] = ex;       lcur[2 * tid + 1] = ex + c0;
    __syncthreads();

    // table write (coalesced): (off<<16) | cnt  (both <= 4096)
    tab[(size_t)blk * NBUCK + tid] =
        ((unsigned int)boff[tid] << 16) | (unsigned int)cnt[tid];
    tab[(size_t)blk * NBUCK + 256 + tid] =
        ((unsigned int)boff[256 + tid] << 16) | (unsigned int)cnt[256 + tid];

    // scatter into LDS, sorted by bucket
    #pragma unroll
    for (int k = 0; k < EPT; k++) {
        const int b = rr[k] >> BSHIFT;
        const int slot = atomicAdd(&lcur[b], 1);
        sorted[slot] = (((unsigned int)(rr[k] & (RPB - 1))) << SBITS) | (unsigned int)ss[k];
    }
    __syncthreads();

    // coalesced writeout: 4096 words = 1024 uint4
    const uint4* s4 = reinterpret_cast<const uint4*>(sorted);
    uint4* o4 = reinterpret_cast<uint4*>(bucketed + (size_t)blk * EPB);
    #pragma unroll
    for (int k = 0; k < EPB / 4 / 256; k++)
        o4[k * 256 + tid] = s4[k * 256 + tid];
}

// ---------------------------------------------------------------------------
// Kernel 3: transpose tab [FBLK][NBUCK] -> tabT [NBUCK][FBLK] (LDS-tiled).
// ---------------------------------------------------------------------------
__global__ __launch_bounds__(256) void transpose_tab_kernel(
    const unsigned int* __restrict__ in, unsigned int* __restrict__ out)
{
    __shared__ unsigned int t[32][33];
    const int tx = threadIdx.x & 31;
    const int ty0 = (threadIdx.x >> 5) * 4;
    const int bb = blockIdx.x * 32;   // bucket base
    const int kb = blockIdx.y * 32;   // blk base
    #pragma unroll
    for (int k = 0; k < 4; k++)
        t[ty0 + k][tx] = in[(size_t)(kb + ty0 + k) * NBUCK + bb + tx];
    __syncthreads();
    #pragma unroll
    for (int k = 0; k < 4; k++)
        out[(size_t)(bb + ty0 + k) * FBLK + kb + tx] = t[tx][ty0 + k];
}

// ---------------------------------------------------------------------------
// Kernel 4: fused per-bucket group + gather. One block (1024 thr) per bucket.
// Thread tid owns fill-block tid's segment for this bucket: two passes
// (count, scatter) over ~8 entries each, then per-receiver msg gather.
// ---------------------------------------------------------------------------
__global__ __launch_bounds__(1024) void bucket_gather_kernel(
    const unsigned int* __restrict__ bucketed,
    const unsigned int* __restrict__ tabT,
    const unsigned int* __restrict__ msgh, float* __restrict__ agg)
{
    __shared__ unsigned int elds[CAP];
    __shared__ int dcnt[RPB];
    __shared__ int dcur[RPB];
    const int tid = threadIdx.x;
    const int b = blockIdx.x;

    const unsigned int tv = tabT[(size_t)b * FBLK + tid];
    const int segc = tv & 0xFFFF;
    const unsigned int* seg = bucketed + (size_t)tid * EPB + (tv >> 16);

    if (tid < RPB) dcnt[tid] = 0;
    __syncthreads();
    for (int i = 0; i < segc; i++)
        atomicAdd(&dcnt[seg[i] >> SBITS], 1);
    __syncthreads();
    if (tid < RPB) dcur[tid] = dcnt[tid];
    __syncthreads();
    #pragma unroll
    for (int off = 1; off < RPB; off <<= 1) {
        int t = 0;
        if (tid < RPB && tid >= off) t = dcur[tid - off];
        __syncthreads();
        if (tid < RPB) dcur[tid] += t;
        __syncthreads();
    }
    if (tid < RPB) dcur[tid] -= dcnt[tid];   // exclusive
    __syncthreads();
    for (int i = 0; i < segc; i++) {
        const unsigned int v = seg[i];
        const int slot = atomicAdd(&dcur[v >> SBITS], 1);
        if (slot < CAP) elds[slot] = v & SMASK;
    }
    __syncthreads();

    // per-receiver gather: half-wave groups; lanes 0..9 handle comps 2c,2c+1
    const int hw = tid >> 5;          // 0..31
    const int c = tid & 31;
    const bool act = c < ND / 2;
    for (int rl = hw; rl < RPB; rl += 32) {
        int end = dcur[rl];
        const int cv = dcnt[rl];
        int st = end - cv;
        if (st < 0) st = 0;
        if (end > CAP) end = CAP;
        float a00 = 0.f, a01 = 0.f, a10 = 0.f, a11 = 0.f;
        float a20 = 0.f, a21 = 0.f, a30 = 0.f, a31 = 0.f;
        int i = st;
        for (; i + 3 < end; i += 4) {
            const int s0 = elds[i + 0];
            const int s1 = elds[i + 1];
            const int s2 = elds[i + 2];
            const int s3 = elds[i + 3];
            if (act) {
                const unsigned int w0 = msgh[s0 * MROW + c];
                const unsigned int w1 = msgh[s1 * MROW + c];
                const unsigned int w2 = msgh[s2 * MROW + c];
                const unsigned int w3 = msgh[s3 * MROW + c];
                const float2 f0 = __half22float2(*reinterpret_cast<const __half2*>(&w0));
                const float2 f1 = __half22float2(*reinterpret_cast<const __half2*>(&w1));
                const float2 f2 = __half22float2(*reinterpret_cast<const __half2*>(&w2));
                const float2 f3 = __half22float2(*reinterpret_cast<const __half2*>(&w3));
                a00 += f0.x; a01 += f0.y;
                a10 += f1.x; a11 += f1.y;
                a20 += f2.x; a21 += f2.y;
                a30 += f3.x; a31 += f3.y;
            }
        }
        for (; i < end; i++) {
            const int s = elds[i];
            if (act) {
                const unsigned int w = msgh[s * MROW + c];
                const float2 f = __half22float2(*reinterpret_cast<const __half2*>(&w));
                a00 += f.x; a01 += f.y;
            }
        }
        if (act) {
            float2 r = make_float2((a00 + a10) + (a20 + a30),
                                   (a01 + a11) + (a21 + a31));
            *reinterpret_cast<float2*>(&agg[((size_t)b * RPB + rl) * ND + 2 * c]) = r;
        }
    }
}

// ---------------------------------------------------------------------------
// Kernel 5: node output MLP (40 -> 64 -> 32 -> 20), 128 nodes per block.
// ---------------------------------------------------------------------------
__global__ __launch_bounds__(256) void node_mlp_kernel(
    const float* __restrict__ logits, const float* __restrict__ hidden,
    const float* __restrict__ agg,
    const float* __restrict__ W1, const float* __restrict__ b1,
    const float* __restrict__ W2, const float* __restrict__ b2,
    const float* __restrict__ W3, const float* __restrict__ b3,
    float* __restrict__ out)
{
    // region A: max(X 40*XS, H2 32*XS, Ol 128*20) = 40*XS floats
    __shared__ float regA[ND2 * XS];
    __shared__ float H1[64 * XS];
    __shared__ float sW1[ND2 * 64], sb1[64], sW2[64 * 32], sb2[32], sW3[32 * ND], sb3[ND];
    const int tid = threadIdx.x;
    const int nb0 = blockIdx.x * NPB;

    lds_fill(sW1, W1, ND2 * 64, tid, 256);
    lds_fill(sb1, b1, 64, tid, 256);
    lds_fill(sW2, W2, 64 * 32, tid, 256);
    lds_fill(sb2, b2, 32, tid, 256);
    lds_fill(sW3, W3, 32 * ND, tid, 256);
    lds_fill(sb3, b3, ND, tid, 256);

    float* Xl = regA;
    if (tid < NPB) {
        const float4 lv = reinterpret_cast<const float4*>(logits)[nb0 + tid];
        Xl[0 * XS + tid] = lv.x; Xl[1 * XS + tid] = lv.y;
        Xl[2 * XS + tid] = lv.z; Xl[3 * XS + tid] = lv.w;
    }
    #pragma unroll
    for (int u = 0; u < 2; u++) {
        const int idx = u * 256 + tid;
        const int n = idx >> 2, qq = idx & 3;
        const float4 hv = reinterpret_cast<const float4*>(hidden)[(size_t)(nb0 + n) * 4 + qq];
        Xl[(4 + qq * 4 + 0) * XS + n] = hv.x;
        Xl[(4 + qq * 4 + 1) * XS + n] = hv.y;
        Xl[(4 + qq * 4 + 2) * XS + n] = hv.z;
        Xl[(4 + qq * 4 + 3) * XS + n] = hv.w;
    }
    // agg -> rows 20..39 (128 nodes x 5 float4 = 640)
    for (int idx = tid; idx < NPB * 5; idx += 256) {
        const int n = idx / 5, qq = idx % 5;
        const float4 av = reinterpret_cast<const float4*>(agg)[(size_t)(nb0 + n) * 5 + qq];
        Xl[(ND + qq * 4 + 0) * XS + n] = av.x;
        Xl[(ND + qq * 4 + 1) * XS + n] = av.y;
        Xl[(ND + qq * 4 + 2) * XS + n] = av.z;
        Xl[(ND + qq * 4 + 3) * XS + n] = av.w;
    }
    __syncthreads();

    mlp3_core<ND2>(tid, Xl, H1, regA /*H2*/, regA /*Ol*/, sW1, sb1, sW2, sb2, sW3, sb3);

    // epilogue: split logits / hidden
    if (tid < NPB) {
        const float* orow = regA + tid * ND;
        reinterpret_cast<float4*>(out)[nb0 + tid] =
            make_float4(orow[0], orow[1], orow[2], orow[3]);
        float4* ho = reinterpret_cast<float4*>(out + (size_t)NN * NLOGIT + (size_t)(nb0 + tid) * NHID);
        #pragma unroll
        for (int k = 0; k < 4; k++)
            ho[k] = make_float4(orow[4 + k*4 + 0], orow[4 + k*4 + 1],
                                orow[4 + k*4 + 2], orow[4 + k*4 + 3]);
    }
}

extern "C" void kernel_launch(void* const* d_in, const int* in_sizes, int n_in,
                              void* d_out, int out_size, void* d_ws, size_t ws_size,
                              hipStream_t stream) {
    const float* logits   = (const float*)d_in[0];
    const float* hidden   = (const float*)d_in[1];
    const int*   senders  = (const int*)d_in[2];
    const int*   receivers= (const int*)d_in[3];
    const float* We1 = (const float*)d_in[4];
    const float* be1 = (const float*)d_in[5];
    const float* We2 = (const float*)d_in[6];
    const float* be2 = (const float*)d_in[7];
    const float* We3 = (const float*)d_in[8];
    const float* be3 = (const float*)d_in[9];
    const float* Wn1 = (const float*)d_in[10];
    const float* bn1 = (const float*)d_in[11];
    const float* Wn2 = (const float*)d_in[12];
    const float* bn2 = (const float*)d_in[13];
    const float* Wn3 = (const float*)d_in[14];
    const float* bn3 = (const float*)d_in[15];
    float* out = (float*)d_out;

    // Workspace layout (~58.6 MB)
    unsigned int* msgh = (unsigned int*)d_ws;          // NN*MROW u32 (16.8 MB, 64B rows)
    float* agg = (float*)(msgh + (size_t)NN * MROW);   // NN*ND floats (21 MB)
    unsigned int* bucketed = (unsigned int*)(agg + (size_t)NN * ND);  // NE u32 (16.8 MB)
    unsigned int* tab  = bucketed + NE;                // FBLK*NBUCK u32 (2 MB)
    unsigned int* tabT = tab + (size_t)FBLK * NBUCK;   // NBUCK*FBLK u32 (2 MB)

    msg_mlp_kernel<<<NN / NPB, 256, 0, stream>>>(
        logits, hidden, We1, be1, We2, be2, We3, be3, msgh);
    bucket_fill_kernel<<<FBLK, 256, 0, stream>>>(senders, receivers, bucketed, tab);
    transpose_tab_kernel<<<dim3(NBUCK / 32, FBLK / 32), 256, 0, stream>>>(tab, tabT);
    bucket_gather_kernel<<<NBUCK, 1024, 0, stream>>>(bucketed, tabT, msgh, agg);
    node_mlp_kernel<<<NN / NPB, 256, 0, stream>>>(
        logits, hidden, agg, Wn1, bn1, Wn2, bn2, Wn3, bn3, out);
}